// Round 6
// baseline (258.342 us; speedup 1.0000x reference)
//
#include <hip/hip_runtime.h>
#include <math.h>

#define MAXM 2048          // >= max distinct dst nodes per pathway (<= EP=2000)
#define BMW  640           // bitmap words: supports N <= 20480
#define BS   1024          // mega block size (16 waves; VGPR<=64 => 2 blocks/CU)
#define NB   2048          // linear hist bins == candidate cap

// monotonic float -> uint key (larger float => larger uint)
__device__ __forceinline__ unsigned fkey(float f){
  unsigned u = __float_as_uint(f);
  return (u & 0x80000000u) ? ~u : (u | 0x80000000u);
}
__device__ __forceinline__ int lbin(float sc, float lo, float scl){
  int b = (int)((sc - lo) * scl);
  return b < 0 ? 0 : (b > NB-1 ? NB-1 : b);
}
// fast tanh via native exp+rcp: 1 - 2/(e^{2x}+1). Only for GATE values
// (softmax-ratio path) — never for selection keys.
__device__ __forceinline__ float fast_tanh(float x){
  float e = __expf(2.f*x);
  return 1.f - 2.f*__builtin_amdgcn_rcpf(e + 1.f);
}
__device__ __forceinline__ void hp_eval(const float* __restrict__ x, int i,
                                        const float* __restrict__ Wp,
                                        const float* __restrict__ bp, float* o){
  float x0 = x[i*3+0], x1 = x[i*3+1], x2 = x[i*3+2];
  #pragma unroll
  for (int j = 0; j < 3; ++j)
    o[j] = fmaxf(x0*Wp[0*3+j] + x1*Wp[1*3+j] + x2*Wp[2*3+j] + bp[j], 0.f);
}

// K1: agg[d] = max(agg[d], hp[s]). agg poison (negative) loses to hp>=0 under
// int atomicMax and to fmaxf in k_h2. Zero-skip + read-check: a stale read only
// causes an extra atomic, never a missed max (atomicMax is the authority).
__global__ void k_edge(const float* __restrict__ x, const int* __restrict__ ei,
                       const float* __restrict__ Wp, const float* __restrict__ bp,
                       float* __restrict__ agg, float* __restrict__ acc,
                       unsigned* __restrict__ counter, int E){
  if (blockIdx.x == 0 && threadIdx.x == 0){ acc[0] = 0.f; counter[0] = 0u; }
  int e = blockIdx.x*blockDim.x + threadIdx.x;
  if (e >= E) return;
  int s = ei[e], d = ei[E+e];
  float o[3]; hp_eval(x, s, Wp, bp, o);
  #pragma unroll
  for (int j = 0; j < 3; ++j)
    if (o[j] > 0.f && o[j] > agg[d*3+j])
      atomicMax((int*)&agg[d*3+j], __float_as_int(o[j]));
}

// K2: h_i = tanh(x@Ws + max(agg_i, hp_i)@Wn + bc), in-place over agg (self-loop fused)
// Keeps libm tanhf: h feeds the selection scores — stay bit-identical there.
__global__ void k_h2(const float* __restrict__ x, float* __restrict__ hb,
                     const float* __restrict__ Wp, const float* __restrict__ bp,
                     const float* __restrict__ Ws, const float* __restrict__ Wn,
                     const float* __restrict__ bc, int N){
  int i = blockIdx.x*blockDim.x + threadIdx.x;
  if (i >= N) return;
  float hp[3]; hp_eval(x, i, Wp, bp, hp);
  float x0 = x[i*3+0], x1 = x[i*3+1], x2 = x[i*3+2];
  float a0 = fmaxf(hb[i*3+0], hp[0]);
  float a1 = fmaxf(hb[i*3+1], hp[1]);
  float a2 = fmaxf(hb[i*3+2], hp[2]);
  float o[3];
  #pragma unroll
  for (int j = 0; j < 3; ++j){
    float v = x0*Ws[0*3+j] + x1*Ws[1*3+j] + x2*Ws[2*3+j]
            + a0*Wn[0*3+j] + a1*Wn[1*3+j] + a2*Wn[2*3+j] + bc[j];
    o[j] = tanhf(v);
  }
  hb[i*3+0] = o[0]; hb[i*3+1] = o[1]; hb[i*3+2] = o[2];
}

// K_mega — R6 ABLATION BUILD: identical to R5 except a duplicate B-sweep
// (kept-alive, no stores) runs before the real one to measure B's marginal
// cost. Output bit-identical. launch_bounds(BS,8) pins VGPR<=64 (2 blocks/CU).
__global__ void __launch_bounds__(BS, 8)
k_mega(const float* __restrict__ h, const int* __restrict__ pe,
       const float* __restrict__ sWl, const float* __restrict__ sbl, const float* __restrict__ sWr,
       const float* __restrict__ pWrel, const float* __restrict__ pWroot, const float* __restrict__ pB,
       const float* __restrict__ gW, const float* __restrict__ gB,
       const float* __restrict__ linW, const float* __restrict__ linb,
       const float* __restrict__ mlpW, const float* __restrict__ mlpb,
       float* __restrict__ spG, float* __restrict__ acc, unsigned* __restrict__ counter,
       unsigned* __restrict__ out, int N, int EP, int K, int P){
  __shared__ unsigned bm[BMW];
  __shared__ int      wpfx[BMW];
  __shared__ float    msum[MAXM*3];
  __shared__ unsigned scrA[NB];       // cnt -> hist (2048 bins / 256-bin radix)
  __shared__ unsigned scrB[NB];       // adot -> cand keys
  __shared__ unsigned candIdx[NB];    // candidate node indices
  __shared__ float    wredf[(BS/64)*2];
  __shared__ float    wredA[(BS/64)*4];
  __shared__ float    wredB[(BS/64)*4];
  __shared__ float    s_mn, s_mx;
  __shared__ float    rlo[3], rsc[3];
  __shared__ int      rb[3];
  __shared__ int      s_r, s_C, s_cc, s_done, s_fused;
  __shared__ unsigned s_uT;

  const int p = blockIdx.x;
  const int tid = threadIdx.x;

  float Wl[9], Wr[9], bl[3], wrel[3], wroot[3], gw[3];
  #pragma unroll
  for (int j = 0; j < 9; ++j){ Wl[j] = sWl[p*9+j]; Wr[j] = sWr[p*9+j]; }
  #pragma unroll
  for (int j = 0; j < 3; ++j){
    bl[j] = sbl[p*3+j]; wrel[j] = pWrel[p*3+j];
    wroot[j] = pWroot[p*3+j]; gw[j] = gW[p*3+j];
  }
  float pbv = pB[p], gbv = gB[p];
  float* sp = spG + (size_t)p*N;

  int*   cnt  = (int*)scrA;
  float* adot = (float*)scrB;

  for (int s = tid; s < MAXM; s += BS){
    cnt[s] = 0; adot[s] = 0.f;
    msum[s*3+0]=0.f; msum[s*3+1]=0.f; msum[s*3+2]=0.f;
  }
  for (int s = tid; s < BMW; s += BS) bm[s] = 0u;
  if (tid == 0){ s_done = 0; s_fused = 0; s_uT = 0u; }
  __syncthreads();

  const int* ps = pe + (size_t)p*2*EP;
  const int* pd = ps + EP;

  // A1: mark dst nodes
  for (int e = tid; e < EP; e += BS) atomicOr(&bm[pd[e]>>5], 1u << (pd[e]&31));
  __syncthreads();
  // A2: popcount + exclusive prefix (single-wave shfl scan)
  if (tid < 64){
    int l = tid, base = l*10;
    int c[10], s = 0;
    #pragma unroll
    for (int q = 0; q < 10; ++q){ c[q] = __popc(bm[base+q]); s += c[q]; }
    int pre = s;
    #pragma unroll
    for (int off = 1; off < 64; off <<= 1){
      int t = __shfl_up(pre, off);
      if (l >= off) pre += t;
    }
    pre -= s;
    #pragma unroll
    for (int q = 0; q < 10; ++q){ wpfx[base+q] = pre; pre += c[q]; }
  }
  __syncthreads();
  // A3: msum/cnt keyed by rank(dst)
  for (int e = tid; e < EP; e += BS){
    int s = ps[e], d = pd[e];
    int r = wpfx[d>>5] + __popc(bm[d>>5] & ((1u << (d&31)) - 1u));
    atomicAdd(&cnt[r], 1);
    atomicAdd(&msum[r*3+0], h[s*3+0]);
    atomicAdd(&msum[r*3+1], h[s*3+1]);
    atomicAdd(&msum[r*3+2], h[s*3+2]);
  }
  __syncthreads();
  // A4: msum -> mean; re-zero cnt (cnt==hist storage => t==0 hist pre-zeroed)
  for (int r = tid; r < MAXM; r += BS){
    int c = cnt[r];
    cnt[r] = 0;
    if (c > 0){
      float inv = 1.f / (float)c;
      msum[r*3+0] *= inv; msum[r*3+1] *= inv; msum[r*3+2] *= inv;
    }
  }
  __syncthreads();
  // A5: adot[rank(d)] += xc(s) . wrel
  for (int e = tid; e < EP; e += BS){
    int s = ps[e], d = pd[e];
    float m0=0.f,m1=0.f,m2=0.f;
    unsigned w = bm[s>>5];
    if ((w >> (s&31)) & 1u){
      int rs = wpfx[s>>5] + __popc(w & ((1u << (s&31)) - 1u));
      m0 = msum[rs*3+0]; m1 = msum[rs*3+1]; m2 = msum[rs*3+2];
    }
    float h0 = h[s*3+0], h1 = h[s*3+1], h2 = h[s*3+2];
    float x0 = fmaxf(m0*Wl[0]+m1*Wl[3]+m2*Wl[6] + bl[0] + h0*Wr[0]+h1*Wr[3]+h2*Wr[6], 0.f);
    float x1 = fmaxf(m0*Wl[1]+m1*Wl[4]+m2*Wl[7] + bl[1] + h0*Wr[1]+h1*Wr[4]+h2*Wr[7], 0.f);
    float x2 = fmaxf(m0*Wl[2]+m1*Wl[5]+m2*Wl[8] + bl[2] + h0*Wr[2]+h1*Wr[5]+h2*Wr[8], 0.f);
    int rd = wpfx[d>>5] + __popc(bm[d>>5] & ((1u << (d&31)) - 1u));
    atomicAdd(&adot[rd], x0*wrel[0] + x1*wrel[1] + x2*wrel[2]);
  }
  __syncthreads();

  // ===== R6 ABLATION: duplicate B-sweep (no stores, results kept alive).
  // Runs BEFORE the real B so peak register liveness is unchanged. The
  // "memory" clobber prevents CSE with the real pass below.
  {
    float mn2 = 3.0e38f, mx2 = -3.0e38f;
    float tl2 = 0.f, tb0 = 0.f, tb1 = 0.f, tb2 = 0.f;
    for (int i = tid; i < N; i += BS){
      float m0=0.f,m1=0.f,m2=0.f,ad=0.f;
      unsigned w = bm[i>>5];
      if ((w >> (i&31)) & 1u){
        int r = wpfx[i>>5] + __popc(w & ((1u << (i&31)) - 1u));
        m0 = msum[r*3+0]; m1 = msum[r*3+1]; m2 = msum[r*3+2];
        ad = adot[r];
      }
      float h0 = h[i*3+0], h1 = h[i*3+1], h2 = h[i*3+2];
      float x0 = fmaxf(m0*Wl[0]+m1*Wl[3]+m2*Wl[6] + bl[0] + h0*Wr[0]+h1*Wr[3]+h2*Wr[6], 0.f);
      float x1 = fmaxf(m0*Wl[1]+m1*Wl[4]+m2*Wl[7] + bl[1] + h0*Wr[1]+h1*Wr[4]+h2*Wr[7], 0.f);
      float x2 = fmaxf(m0*Wl[2]+m1*Wl[5]+m2*Wl[8] + bl[2] + h0*Wr[2]+h1*Wr[5]+h2*Wr[8], 0.f);
      float sc = ad + x0*wroot[0]+x1*wroot[1]+x2*wroot[2] + pbv;
      mn2 = fminf(mn2, sc); mx2 = fmaxf(mx2, sc);
      float tt = fast_tanh(sc);
      float g = fminf(fmaxf(tt*(x0*gw[0]+x1*gw[1]+x2*gw[2]) + gbv, -60.f), 60.f);
      float e = __expf(g);
      float et = e * tt;
      tl2 += e; tb0 += et*x0; tb1 += et*x1; tb2 += et*x2;
    }
    asm volatile("" :: "v"(mn2), "v"(mx2), "v"(tl2), "v"(tb0), "v"(tb1), "v"(tb2));
  }
  asm volatile("" ::: "memory");

  // B: fused sweep — score -> sp, min/max, gate totals over ALL nodes
  float mn = 3.0e38f, mx = -3.0e38f;
  float tl = 0.f, ta0 = 0.f, ta1 = 0.f, ta2 = 0.f;
  for (int i = tid; i < N; i += BS){
    float m0=0.f,m1=0.f,m2=0.f,ad=0.f;
    unsigned w = bm[i>>5];
    if ((w >> (i&31)) & 1u){
      int r = wpfx[i>>5] + __popc(w & ((1u << (i&31)) - 1u));
      m0 = msum[r*3+0]; m1 = msum[r*3+1]; m2 = msum[r*3+2];
      ad = adot[r];
    }
    float h0 = h[i*3+0], h1 = h[i*3+1], h2 = h[i*3+2];
    float x0 = fmaxf(m0*Wl[0]+m1*Wl[3]+m2*Wl[6] + bl[0] + h0*Wr[0]+h1*Wr[3]+h2*Wr[6], 0.f);
    float x1 = fmaxf(m0*Wl[1]+m1*Wl[4]+m2*Wl[7] + bl[1] + h0*Wr[1]+h1*Wr[4]+h2*Wr[7], 0.f);
    float x2 = fmaxf(m0*Wl[2]+m1*Wl[5]+m2*Wl[8] + bl[2] + h0*Wr[2]+h1*Wr[5]+h2*Wr[8], 0.f);
    float sc = ad + x0*wroot[0]+x1*wroot[1]+x2*wroot[2] + pbv;
    sp[i] = sc;
    mn = fminf(mn, sc); mx = fmaxf(mx, sc);
    float tt = fast_tanh(sc);
    float g = fminf(fmaxf(tt*(x0*gw[0]+x1*gw[1]+x2*gw[2]) + gbv, -60.f), 60.f);
    float e = __expf(g);
    float et = e * tt;
    tl += e; ta0 += et*x0; ta1 += et*x1; ta2 += et*x2;
  }
  #pragma unroll
  for (int off = 32; off > 0; off >>= 1){
    mn  = fminf(mn, __shfl_down(mn, off));
    mx  = fmaxf(mx, __shfl_down(mx, off));
    tl  += __shfl_down(tl,  off); ta0 += __shfl_down(ta0, off);
    ta1 += __shfl_down(ta1, off); ta2 += __shfl_down(ta2, off);
  }
  if ((tid & 63) == 0){
    int w = tid >> 6;
    wredf[w*2+0] = mn; wredf[w*2+1] = mx;
    wredA[w*4+0]=tl; wredA[w*4+1]=ta0; wredA[w*4+2]=ta1; wredA[w*4+3]=ta2;
  }
  __syncthreads();
  if (tid == 0){
    float a = 3.0e38f, b = -3.0e38f;
    for (int w = 0; w < BS/64; ++w){ a = fminf(a, wredf[w*2+0]); b = fmaxf(b, wredf[w*2+1]); }
    s_mn = a; s_mx = b; s_r = K;
    if (!(b > a)){ s_uT = fkey(a); s_done = 1; s_fused = 1; }  // all equal: none dropped
  }
  __syncthreads();

  unsigned* hist = scrA;    // overlays cnt (dead; pre-zeroed by A4 for t==0)
  unsigned* cand = scrB;    // overlays adot (dead; gate math needs only msum)

  float dl = 0.f, d0 = 0.f, d1 = 0.f, d2 = 0.f;   // drop-sum registers

  for (int t = 0; t < 3; ++t){
    __syncthreads();
    if (s_done) break;
    float lo, hi;
    if (t == 0){ lo = s_mn; hi = s_mx; }
    else { lo = rlo[t-1] + rb[t-1]/rsc[t-1]; hi = rlo[t-1] + (rb[t-1]+1)/rsc[t-1]; }
    float scl = 2047.0f / (hi - lo);
    if (!(hi > lo) || !(scl < 1e37f)){
      if (tid == 0){ s_uT = fkey(lo); s_done = 1; }   // s_fused stays 0 -> fallback
      __syncthreads();
      continue;
    }
    if (t > 0){
      for (int b = tid; b < NB; b += BS) hist[b] = 0u;
      __syncthreads();
    }
    if (t == 0){
      if ((N & 3) == 0){
        int G = N >> 2;
        for (int g = tid; g < G; g += BS){
          float4 v = ((const float4*)sp)[g];
          atomicAdd(&hist[lbin(v.x, lo, scl)], 1u);
          atomicAdd(&hist[lbin(v.y, lo, scl)], 1u);
          atomicAdd(&hist[lbin(v.z, lo, scl)], 1u);
          atomicAdd(&hist[lbin(v.w, lo, scl)], 1u);
        }
      } else {
        for (int i = tid; i < N; i += BS) atomicAdd(&hist[lbin(sp[i], lo, scl)], 1u);
      }
    } else {
      for (int i = tid; i < N; i += BS){
        float sc = sp[i];
        bool act = true;
        for (int q = 0; q < t; ++q) act = act && (lbin(sc, rlo[q], rsc[q]) == rb[q]);
        if (act) atomicAdd(&hist[lbin(sc, lo, scl)], 1u);
      }
    }
    __syncthreads();
    // pick over 2048 bins: lane l owns bins [32l, 32l+32)
    if (tid < 64){
      int l = tid;
      unsigned s = 0;
      for (int q = 0; q < 32; ++q) s += hist[l*32+q];
      unsigned S = s;
      #pragma unroll
      for (int off = 1; off < 64; off <<= 1){
        unsigned u2 = __shfl_down(S, off);
        if (l + off < 64) S += u2;
      }
      unsigned suf = S - s;               // suffix over lanes > l
      unsigned r = (unsigned)s_r;
      int b = -1; unsigned sufnext = 0, cb = 0;
      for (int q = 31; q >= 0; --q){
        unsigned c = hist[l*32+q];
        unsigned nsuf = suf + c;
        if (nsuf >= r && suf < r){ b = l*32+q; sufnext = suf; cb = c; }
        suf = nsuf;
      }
      if (b >= 0){
        rb[t] = b; rlo[t] = lo; rsc[t] = scl;
        s_r = (int)(r - sufnext);
        s_C = (int)cb;
      }
    }
    __syncthreads();
    int C = s_C;
    if (C <= NB){
      if (tid == 0) s_cc = 0;
      __syncthreads();
      // compact: candidates (key+idx) AND drop-sum accumulation in one sweep.
      // t==0 fast path: float4 loads, single-bin predicate.
      if (t == 0 && (N & 3) == 0){
        const int b0 = rb[0];
        const float l0 = rlo[0], s0 = rsc[0];
        int G = N >> 2;
        for (int g = tid; g < G; g += BS){
          float4 v = ((const float4*)sp)[g];
          #pragma unroll
          for (int u = 0; u < 4; ++u){
            float sc = (u==0)?v.x:((u==1)?v.y:((u==2)?v.z:v.w));
            int b = lbin(sc, l0, s0);
            if (b == b0){
              int ix = atomicAdd(&s_cc, 1);
              if (ix < NB){ cand[ix] = fkey(sc); candIdx[ix] = (unsigned)(g*4+u); }
            } else if (b < b0){
              int i = g*4+u;
              float m0=0.f,m1=0.f,m2=0.f;
              unsigned w = bm[i>>5];
              if ((w >> (i&31)) & 1u){
                int r = wpfx[i>>5] + __popc(w & ((1u << (i&31)) - 1u));
                m0 = msum[r*3+0]; m1 = msum[r*3+1]; m2 = msum[r*3+2];
              }
              float h0 = h[i*3+0], h1 = h[i*3+1], h2 = h[i*3+2];
              float x0 = fmaxf(m0*Wl[0]+m1*Wl[3]+m2*Wl[6] + bl[0] + h0*Wr[0]+h1*Wr[3]+h2*Wr[6], 0.f);
              float x1 = fmaxf(m0*Wl[1]+m1*Wl[4]+m2*Wl[7] + bl[1] + h0*Wr[1]+h1*Wr[4]+h2*Wr[7], 0.f);
              float x2 = fmaxf(m0*Wl[2]+m1*Wl[5]+m2*Wl[8] + bl[2] + h0*Wr[2]+h1*Wr[5]+h2*Wr[8], 0.f);
              float tt = fast_tanh(sc);
              float gg = fminf(fmaxf(tt*(x0*gw[0]+x1*gw[1]+x2*gw[2]) + gbv, -60.f), 60.f);
              float e = __expf(gg);
              float et = e * tt;
              dl += e; d0 += et*x0; d1 += et*x1; d2 += et*x2;
            }
          }
        }
      } else {
        for (int i = tid; i < N; i += BS){
          float sc = sp[i];
          bool iscand = true, isdrop = false;
          for (int q = 0; q <= t; ++q){
            int b = lbin(sc, rlo[q], rsc[q]);
            if (b != rb[q]){ iscand = false; isdrop = (b < rb[q]); break; }
          }
          if (iscand){
            int ix = atomicAdd(&s_cc, 1);
            if (ix < NB){ cand[ix] = fkey(sc); candIdx[ix] = (unsigned)i; }
          } else if (isdrop){
            float m0=0.f,m1=0.f,m2=0.f;
            unsigned w = bm[i>>5];
            if ((w >> (i&31)) & 1u){
              int r = wpfx[i>>5] + __popc(w & ((1u << (i&31)) - 1u));
              m0 = msum[r*3+0]; m1 = msum[r*3+1]; m2 = msum[r*3+2];
            }
            float h0 = h[i*3+0], h1 = h[i*3+1], h2 = h[i*3+2];
            float x0 = fmaxf(m0*Wl[0]+m1*Wl[3]+m2*Wl[6] + bl[0] + h0*Wr[0]+h1*Wr[3]+h2*Wr[6], 0.f);
            float x1 = fmaxf(m0*Wl[1]+m1*Wl[4]+m2*Wl[7] + bl[1] + h0*Wr[1]+h1*Wr[4]+h2*Wr[7], 0.f);
            float x2 = fmaxf(m0*Wl[2]+m1*Wl[5]+m2*Wl[8] + bl[2] + h0*Wr[2]+h1*Wr[5]+h2*Wr[8], 0.f);
            float tt = fast_tanh(sc);
            float gg = fminf(fmaxf(tt*(x0*gw[0]+x1*gw[1]+x2*gw[2]) + gbv, -60.f), 60.f);
            float e = __expf(gg);
            float et = e * tt;
            dl += e; d0 += et*x0; d1 += et*x1; d2 += et*x2;
          }
        }
      }
      __syncthreads();
      // exact 4-pass radix over cand[0..C), single wave, no block barriers
      if (tid < 64){
        int l = tid;
        unsigned pref = 0u, mask = 0u;
        int r = s_r;
        #pragma unroll
        for (int pass = 0; pass < 4; ++pass){
          int shift = 24 - 8*pass;
          hist[4*l+0]=0u; hist[4*l+1]=0u; hist[4*l+2]=0u; hist[4*l+3]=0u;
          asm volatile("s_waitcnt lgkmcnt(0)" ::: "memory");
          for (int j = l; j < C; j += 64){
            unsigned u = cand[j];
            if ((u & mask) == pref) atomicAdd(&hist[(u>>shift)&255u], 1u);
          }
          asm volatile("s_waitcnt lgkmcnt(0)" ::: "memory");
          unsigned h0 = hist[4*l+0], h1 = hist[4*l+1], h2 = hist[4*l+2], h3 = hist[4*l+3];
          unsigned ssum = h0+h1+h2+h3;
          unsigned S = ssum;
          #pragma unroll
          for (int off = 1; off < 64; off <<= 1){
            unsigned u2 = __shfl_down(S, off);
            if (l + off < 64) S += u2;
          }
          unsigned Snext = S - ssum;
          unsigned rr = (unsigned)r;
          unsigned suf3 = h3 + Snext;
          unsigned suf2 = h2 + suf3;
          unsigned suf1 = h1 + suf2;
          unsigned suf0 = h0 + suf1;
          int b = -1; unsigned sufn = 0;
          if      (suf3 >= rr && Snext < rr){ b = 4*l+3; sufn = Snext; }
          else if (suf2 >= rr && suf3  < rr){ b = 4*l+2; sufn = suf3; }
          else if (suf1 >= rr && suf2  < rr){ b = 4*l+1; sufn = suf2; }
          else if (suf0 >= rr && suf1  < rr){ b = 4*l+0; sufn = suf1; }
          unsigned long long ball = __ballot(b >= 0);
          int src = __ffsll(ball) - 1;
          b    = __shfl(b, src);
          sufn = (unsigned)__shfl((int)sufn, src);
          pref |= (unsigned)b << shift;
          mask |= 255u << shift;
          r = (int)(rr - sufn);
        }
        if (l == 0) s_uT = pref;
      }
      if (tid == 0){ s_done = 1; s_fused = 1; }
      __syncthreads();
      // candidate fix: subtract in-bucket dropped (key < uT)
      {
        const unsigned uTl = s_uT;
        for (int j = tid; j < C; j += BS){
          if (cand[j] < uTl){
            int i = (int)candIdx[j];
            float sc = sp[i];
            float m0=0.f,m1=0.f,m2=0.f;
            unsigned w = bm[i>>5];
            if ((w >> (i&31)) & 1u){
              int r = wpfx[i>>5] + __popc(w & ((1u << (i&31)) - 1u));
              m0 = msum[r*3+0]; m1 = msum[r*3+1]; m2 = msum[r*3+2];
            }
            float h0 = h[i*3+0], h1 = h[i*3+1], h2 = h[i*3+2];
            float x0 = fmaxf(m0*Wl[0]+m1*Wl[3]+m2*Wl[6] + bl[0] + h0*Wr[0]+h1*Wr[3]+h2*Wr[6], 0.f);
            float x1 = fmaxf(m0*Wl[1]+m1*Wl[4]+m2*Wl[7] + bl[1] + h0*Wr[1]+h1*Wr[4]+h2*Wr[7], 0.f);
            float x2 = fmaxf(m0*Wl[2]+m1*Wl[5]+m2*Wl[8] + bl[2] + h0*Wr[2]+h1*Wr[5]+h2*Wr[8], 0.f);
            float tt = fast_tanh(sc);
            float gg = fminf(fmaxf(tt*(x0*gw[0]+x1*gw[1]+x2*gw[2]) + gbv, -60.f), 60.f);
            float e = __expf(gg);
            float et = e * tt;
            dl += e; d0 += et*x0; d1 += et*x1; d2 += et*x2;
          }
        }
      }
    } else if (t == 2){
      if (tid == 0){ s_uT = fkey(lo + rb[t]/scl); s_done = 1; }  // safety; s_fused=0
      __syncthreads();
    }
  }
  __syncthreads();
  const unsigned uT = s_uT;

  // Fallback correction (rare degenerate paths only): full N sweep
  if (!s_fused){
    for (int i = tid; i < N; i += BS){
      float sc = sp[i];
      if (fkey(sc) < uT){
        float m0=0.f,m1=0.f,m2=0.f;
        unsigned w = bm[i>>5];
        if ((w >> (i&31)) & 1u){
          int r = wpfx[i>>5] + __popc(w & ((1u << (i&31)) - 1u));
          m0 = msum[r*3+0]; m1 = msum[r*3+1]; m2 = msum[r*3+2];
        }
        float h0 = h[i*3+0], h1 = h[i*3+1], h2 = h[i*3+2];
        float x0 = fmaxf(m0*Wl[0]+m1*Wl[3]+m2*Wl[6] + bl[0] + h0*Wr[0]+h1*Wr[3]+h2*Wr[6], 0.f);
        float x1 = fmaxf(m0*Wl[1]+m1*Wl[4]+m2*Wl[7] + bl[1] + h0*Wr[1]+h1*Wr[4]+h2*Wr[7], 0.f);
        float x2 = fmaxf(m0*Wl[2]+m1*Wl[5]+m2*Wl[8] + bl[2] + h0*Wr[2]+h1*Wr[5]+h2*Wr[8], 0.f);
        float tt = fast_tanh(sc);
        float gg = fminf(fmaxf(tt*(x0*gw[0]+x1*gw[1]+x2*gw[2]) + gbv, -60.f), 60.f);
        float e = __expf(gg);
        float et = e * tt;
        dl += e; d0 += et*x0; d1 += et*x1; d2 += et*x2;
      }
    }
  }
  #pragma unroll
  for (int off = 32; off > 0; off >>= 1){
    dl += __shfl_down(dl, off); d0 += __shfl_down(d0, off);
    d1 += __shfl_down(d1, off); d2 += __shfl_down(d2, off);
  }
  if ((tid & 63) == 0){
    int w = tid >> 6;
    wredB[w*4+0]=dl; wredB[w*4+1]=d0; wredB[w*4+2]=d1; wredB[w*4+3]=d2;
  }
  __syncthreads();
  if (tid == 0){
    float L=0.f, A0=0.f, A1=0.f, A2=0.f;
    for (int w = 0; w < BS/64; ++w){
      L  += wredA[w*4+0] - wredB[w*4+0];
      A0 += wredA[w*4+1] - wredB[w*4+1];
      A1 += wredA[w*4+2] - wredB[w*4+2];
      A2 += wredA[w*4+3] - wredB[w*4+3];
    }
    float inv = 1.f / L;
    float r0 = fmaxf(A0*inv, 0.f);
    float r1 = fmaxf(A1*inv, 0.f);
    float r2 = fmaxf(A2*inv, 0.f);
    float rr = fmaxf(r0*linW[0] + r1*linW[1] + r2*linW[2] + linb[0], 0.f);
    atomicAdd(acc, rr * mlpW[p]);            // relu(relu(x)) == relu(x)
    __threadfence();
    unsigned old = atomicAdd(counter, 1u);
    if (old == (unsigned)(P-1)){
      __threadfence();
      float z = atomicAdd(acc, 0.f) + mlpb[0];   // atomic read: full sum visible
      float a = 1.f / (1.f + expf(-z));
      unsigned A = __float_as_uint(a);
      unsigned B = (A + 0x7FFFu + ((A >> 16) & 1u)) >> 16;   // bf16 RNE bits
      out[0] = (A & 0xFFFF0000u) | (B & 0xFFFFu);            // dual-format store
    }
  }
}

// ================= launcher: 3 dispatches =================
extern "C" void kernel_launch(void* const* d_in, const int* in_sizes, int n_in,
                              void* d_out, int out_size, void* d_ws, size_t ws_size,
                              hipStream_t stream){
  const float* x      = (const float*)d_in[0];
  const int*   ei     = (const int*)  d_in[1];
  const int*   pe     = (const int*)  d_in[2];
  const float* W_pool = (const float*)d_in[3];
  const float* b_pool = (const float*)d_in[4];
  const float* W_self = (const float*)d_in[5];
  const float* W_neigh= (const float*)d_in[6];
  const float* b_conv = (const float*)d_in[7];
  const float* sWl    = (const float*)d_in[8];
  const float* sbl    = (const float*)d_in[9];
  const float* sWr    = (const float*)d_in[10];
  const float* pWrel  = (const float*)d_in[11];
  const float* pWroot = (const float*)d_in[12];
  const float* pB     = (const float*)d_in[13];
  const float* gW     = (const float*)d_in[14];
  const float* gB     = (const float*)d_in[15];
  const float* linW   = (const float*)d_in[16];
  const float* linb   = (const float*)d_in[17];
  const float* mlpW   = (const float*)d_in[18];
  const float* mlpb   = (const float*)d_in[19];

  const int N  = in_sizes[0] / 3;
  const int E  = in_sizes[1] / 2;
  const int P  = in_sizes[13];
  const int EP = in_sizes[2] / (2 * P);
  const int K  = (4*N + 4) / 5;          // ceil(0.8*N)

  // ws layout (float elements): [0]=acc, [1]=counter, pad; [16,16+3N)=agg/h; sp after.
  float*    ws      = (float*)d_ws;
  float*    acc     = ws;
  unsigned* counter = (unsigned*)(ws + 1);
  float*    agg     = ws + 16;           // becomes h in-place after k_h2
  float*    h       = agg;
  float*    spG     = ws + 16 + (size_t)3*N;

  k_edge<<<(E+255)/256, 256, 0, stream>>>(x, ei, W_pool, b_pool, agg, acc, counter, E);
  k_h2  <<<(N+255)/256, 256, 0, stream>>>(x, agg, W_pool, b_pool,
                                          W_self, W_neigh, b_conv, N);
  k_mega<<<P, BS, 0, stream>>>(h, pe, sWl, sbl, sWr, pWrel, pWroot, pB, gW, gB,
                               linW, linb, mlpW, mlpb,
                               spG, acc, counter, (unsigned*)d_out, N, EP, K, P);
}

// Round 7
// 240.390 us; speedup vs baseline: 1.0747x; 1.0747x over previous
//
#include <hip/hip_runtime.h>
#include <math.h>

#define MAXM 2048          // >= max distinct dst nodes per pathway (<= EP=2000)
#define BMW  640           // bitmap words: supports N <= 20480
#define BS   1024          // mega block size (16 waves; VGPR<=64 => 2 blocks/CU)
#define NB   2048          // linear hist bins == candidate cap

// monotonic float -> uint key (larger float => larger uint)
__device__ __forceinline__ unsigned fkey(float f){
  unsigned u = __float_as_uint(f);
  return (u & 0x80000000u) ? ~u : (u | 0x80000000u);
}
__device__ __forceinline__ int lbin(float sc, float lo, float scl){
  int b = (int)((sc - lo) * scl);
  return b < 0 ? 0 : (b > NB-1 ? NB-1 : b);
}
// fast tanh via native exp+rcp: 1 - 2/(e^{2x}+1). Only for GATE values
// (softmax-ratio path) — never for selection keys.
__device__ __forceinline__ float fast_tanh(float x){
  float e = __expf(2.f*x);
  return 1.f - 2.f*__builtin_amdgcn_rcpf(e + 1.f);
}
__device__ __forceinline__ void hp_eval(const float* __restrict__ x, int i,
                                        const float* __restrict__ Wp,
                                        const float* __restrict__ bp, float* o){
  float x0 = x[i*3+0], x1 = x[i*3+1], x2 = x[i*3+2];
  #pragma unroll
  for (int j = 0; j < 3; ++j)
    o[j] = fmaxf(x0*Wp[0*3+j] + x1*Wp[1*3+j] + x2*Wp[2*3+j] + bp[j], 0.f);
}

// K1: agg[d] = max(agg[d], hp[s]). agg poison (negative) loses to hp>=0 under
// int atomicMax and to fmaxf in k_h2. Zero-skip + read-check: a stale read only
// causes an extra atomic, never a missed max (atomicMax is the authority).
__global__ void k_edge(const float* __restrict__ x, const int* __restrict__ ei,
                       const float* __restrict__ Wp, const float* __restrict__ bp,
                       float* __restrict__ agg, float* __restrict__ acc,
                       unsigned* __restrict__ counter, int E){
  if (blockIdx.x == 0 && threadIdx.x == 0){ acc[0] = 0.f; counter[0] = 0u; }
  int e = blockIdx.x*blockDim.x + threadIdx.x;
  if (e >= E) return;
  int s = ei[e], d = ei[E+e];
  float o[3]; hp_eval(x, s, Wp, bp, o);
  #pragma unroll
  for (int j = 0; j < 3; ++j)
    if (o[j] > 0.f && o[j] > agg[d*3+j])
      atomicMax((int*)&agg[d*3+j], __float_as_int(o[j]));
}

// K2: h_i = tanh(x@Ws + max(agg_i, hp_i)@Wn + bc), in-place over agg (self-loop fused)
// Keeps libm tanhf: h feeds the selection scores — stay bit-identical there.
__global__ void k_h2(const float* __restrict__ x, float* __restrict__ hb,
                     const float* __restrict__ Wp, const float* __restrict__ bp,
                     const float* __restrict__ Ws, const float* __restrict__ Wn,
                     const float* __restrict__ bc, int N){
  int i = blockIdx.x*blockDim.x + threadIdx.x;
  if (i >= N) return;
  float hp[3]; hp_eval(x, i, Wp, bp, hp);
  float x0 = x[i*3+0], x1 = x[i*3+1], x2 = x[i*3+2];
  float a0 = fmaxf(hb[i*3+0], hp[0]);
  float a1 = fmaxf(hb[i*3+1], hp[1]);
  float a2 = fmaxf(hb[i*3+2], hp[2]);
  float o[3];
  #pragma unroll
  for (int j = 0; j < 3; ++j){
    float v = x0*Ws[0*3+j] + x1*Ws[1*3+j] + x2*Ws[2*3+j]
            + a0*Wn[0*3+j] + a1*Wn[1*3+j] + a2*Wn[2*3+j] + bc[j];
    o[j] = tanhf(v);
  }
  hb[i*3+0] = o[0]; hb[i*3+1] = o[1]; hb[i*3+2] = o[2];
}

// K_mega: one 1024-thr block per pathway (grid=P=300; 2 blocks/CU co-resident).
// A: EP aggregation (LDS, rank-compressed). A4 re-zeroes cnt => hist pre-zeroed.
// B: fused sweep — score -> sp, min/max, gate-softmax totals over ALL nodes.
// Select: linear 2048-bin hist (float4) -> pick -> compact (float4, fused
//   drop-subtract + candidate key+idx) -> single-wave 4-pass radix over 4
//   disjoint pre-zeroed 256-bin regions -> candidate fix => exact uT.
// Degenerate paths -> full fallback correction sweep (exactness kept).
__global__ void __launch_bounds__(BS)
k_mega(const float* __restrict__ h, const int* __restrict__ pe,
       const float* __restrict__ sWl, const float* __restrict__ sbl, const float* __restrict__ sWr,
       const float* __restrict__ pWrel, const float* __restrict__ pWroot, const float* __restrict__ pB,
       const float* __restrict__ gW, const float* __restrict__ gB,
       const float* __restrict__ linW, const float* __restrict__ linb,
       const float* __restrict__ mlpW, const float* __restrict__ mlpb,
       float* __restrict__ spG, float* __restrict__ acc, unsigned* __restrict__ counter,
       unsigned* __restrict__ out, int N, int EP, int K, int P){
  __shared__ unsigned bm[BMW];
  __shared__ int      wpfx[BMW];
  __shared__ float    msum[MAXM*3];
  __shared__ unsigned scrA[NB];       // cnt -> hist (2048 bins / 4x256-bin radix)
  __shared__ unsigned scrB[NB];       // adot -> cand keys
  __shared__ unsigned candIdx[NB];    // candidate node indices
  __shared__ float    wredf[(BS/64)*2];
  __shared__ float    wredA[(BS/64)*4];
  __shared__ float    wredB[(BS/64)*4];
  __shared__ float    s_mn, s_mx;
  __shared__ float    rlo[3], rsc[3];
  __shared__ int      rb[3];
  __shared__ int      s_r, s_C, s_cc, s_done, s_fused;
  __shared__ unsigned s_uT;

  const int p = blockIdx.x;
  const int tid = threadIdx.x;

  float Wl[9], Wr[9], bl[3], wrel[3], wroot[3], gw[3];
  #pragma unroll
  for (int j = 0; j < 9; ++j){ Wl[j] = sWl[p*9+j]; Wr[j] = sWr[p*9+j]; }
  #pragma unroll
  for (int j = 0; j < 3; ++j){
    bl[j] = sbl[p*3+j]; wrel[j] = pWrel[p*3+j];
    wroot[j] = pWroot[p*3+j]; gw[j] = gW[p*3+j];
  }
  float pbv = pB[p], gbv = gB[p];
  float* sp = spG + (size_t)p*N;

  int*   cnt  = (int*)scrA;
  float* adot = (float*)scrB;

  for (int s = tid; s < MAXM; s += BS){
    cnt[s] = 0; adot[s] = 0.f;
    msum[s*3+0]=0.f; msum[s*3+1]=0.f; msum[s*3+2]=0.f;
  }
  for (int s = tid; s < BMW; s += BS) bm[s] = 0u;
  if (tid == 0){ s_done = 0; s_fused = 0; s_uT = 0u; }
  __syncthreads();

  const int* ps = pe + (size_t)p*2*EP;
  const int* pd = ps + EP;

  // A1: mark dst nodes
  for (int e = tid; e < EP; e += BS) atomicOr(&bm[pd[e]>>5], 1u << (pd[e]&31));
  __syncthreads();
  // A2: popcount + exclusive prefix (single-wave shfl scan)
  if (tid < 64){
    int l = tid, base = l*10;
    int c[10], s = 0;
    #pragma unroll
    for (int q = 0; q < 10; ++q){ c[q] = __popc(bm[base+q]); s += c[q]; }
    int pre = s;
    #pragma unroll
    for (int off = 1; off < 64; off <<= 1){
      int t = __shfl_up(pre, off);
      if (l >= off) pre += t;
    }
    pre -= s;
    #pragma unroll
    for (int q = 0; q < 10; ++q){ wpfx[base+q] = pre; pre += c[q]; }
  }
  __syncthreads();
  // A3: msum/cnt keyed by rank(dst)
  for (int e = tid; e < EP; e += BS){
    int s = ps[e], d = pd[e];
    int r = wpfx[d>>5] + __popc(bm[d>>5] & ((1u << (d&31)) - 1u));
    atomicAdd(&cnt[r], 1);
    atomicAdd(&msum[r*3+0], h[s*3+0]);
    atomicAdd(&msum[r*3+1], h[s*3+1]);
    atomicAdd(&msum[r*3+2], h[s*3+2]);
  }
  __syncthreads();
  // A4: msum -> mean; re-zero cnt (cnt==hist storage => t==0 hist pre-zeroed)
  for (int r = tid; r < MAXM; r += BS){
    int c = cnt[r];
    cnt[r] = 0;
    if (c > 0){
      float inv = 1.f / (float)c;
      msum[r*3+0] *= inv; msum[r*3+1] *= inv; msum[r*3+2] *= inv;
    }
  }
  __syncthreads();
  // A5: adot[rank(d)] += xc(s) . wrel
  for (int e = tid; e < EP; e += BS){
    int s = ps[e], d = pd[e];
    float m0=0.f,m1=0.f,m2=0.f;
    unsigned w = bm[s>>5];
    if ((w >> (s&31)) & 1u){
      int rs = wpfx[s>>5] + __popc(w & ((1u << (s&31)) - 1u));
      m0 = msum[rs*3+0]; m1 = msum[rs*3+1]; m2 = msum[rs*3+2];
    }
    float h0 = h[s*3+0], h1 = h[s*3+1], h2 = h[s*3+2];
    float x0 = fmaxf(m0*Wl[0]+m1*Wl[3]+m2*Wl[6] + bl[0] + h0*Wr[0]+h1*Wr[3]+h2*Wr[6], 0.f);
    float x1 = fmaxf(m0*Wl[1]+m1*Wl[4]+m2*Wl[7] + bl[1] + h0*Wr[1]+h1*Wr[4]+h2*Wr[7], 0.f);
    float x2 = fmaxf(m0*Wl[2]+m1*Wl[5]+m2*Wl[8] + bl[2] + h0*Wr[2]+h1*Wr[5]+h2*Wr[8], 0.f);
    int rd = wpfx[d>>5] + __popc(bm[d>>5] & ((1u << (d&31)) - 1u));
    atomicAdd(&adot[rd], x0*wrel[0] + x1*wrel[1] + x2*wrel[2]);
  }
  __syncthreads();

  // B: fused sweep — score -> sp, min/max, gate totals over ALL nodes
  float mn = 3.0e38f, mx = -3.0e38f;
  float tl = 0.f, ta0 = 0.f, ta1 = 0.f, ta2 = 0.f;
  for (int i = tid; i < N; i += BS){
    float m0=0.f,m1=0.f,m2=0.f,ad=0.f;
    unsigned w = bm[i>>5];
    if ((w >> (i&31)) & 1u){
      int r = wpfx[i>>5] + __popc(w & ((1u << (i&31)) - 1u));
      m0 = msum[r*3+0]; m1 = msum[r*3+1]; m2 = msum[r*3+2];
      ad = adot[r];
    }
    float h0 = h[i*3+0], h1 = h[i*3+1], h2 = h[i*3+2];
    float x0 = fmaxf(m0*Wl[0]+m1*Wl[3]+m2*Wl[6] + bl[0] + h0*Wr[0]+h1*Wr[3]+h2*Wr[6], 0.f);
    float x1 = fmaxf(m0*Wl[1]+m1*Wl[4]+m2*Wl[7] + bl[1] + h0*Wr[1]+h1*Wr[4]+h2*Wr[7], 0.f);
    float x2 = fmaxf(m0*Wl[2]+m1*Wl[5]+m2*Wl[8] + bl[2] + h0*Wr[2]+h1*Wr[5]+h2*Wr[8], 0.f);
    float sc = ad + x0*wroot[0]+x1*wroot[1]+x2*wroot[2] + pbv;
    sp[i] = sc;
    mn = fminf(mn, sc); mx = fmaxf(mx, sc);
    float tt = fast_tanh(sc);
    float g = fminf(fmaxf(tt*(x0*gw[0]+x1*gw[1]+x2*gw[2]) + gbv, -60.f), 60.f);
    float e = __expf(g);
    float et = e * tt;
    tl += e; ta0 += et*x0; ta1 += et*x1; ta2 += et*x2;
  }
  #pragma unroll
  for (int off = 32; off > 0; off >>= 1){
    mn  = fminf(mn, __shfl_down(mn, off));
    mx  = fmaxf(mx, __shfl_down(mx, off));
    tl  += __shfl_down(tl,  off); ta0 += __shfl_down(ta0, off);
    ta1 += __shfl_down(ta1, off); ta2 += __shfl_down(ta2, off);
  }
  if ((tid & 63) == 0){
    int w = tid >> 6;
    wredf[w*2+0] = mn; wredf[w*2+1] = mx;
    wredA[w*4+0]=tl; wredA[w*4+1]=ta0; wredA[w*4+2]=ta1; wredA[w*4+3]=ta2;
  }
  __syncthreads();
  if (tid == 0){
    float a = 3.0e38f, b = -3.0e38f;
    for (int w = 0; w < BS/64; ++w){ a = fminf(a, wredf[w*2+0]); b = fmaxf(b, wredf[w*2+1]); }
    s_mn = a; s_mx = b; s_r = K;
    if (!(b > a)){ s_uT = fkey(a); s_done = 1; s_fused = 1; }  // all equal: none dropped
  }
  __syncthreads();

  unsigned* hist = scrA;    // overlays cnt (dead; pre-zeroed by A4 for t==0)
  unsigned* cand = scrB;    // overlays adot (dead; gate math needs only msum)

  float dl = 0.f, d0 = 0.f, d1 = 0.f, d2 = 0.f;   // drop-sum registers

  for (int t = 0; t < 3; ++t){
    __syncthreads();
    if (s_done) break;
    float lo, hi;
    if (t == 0){ lo = s_mn; hi = s_mx; }
    else { lo = rlo[t-1] + rb[t-1]/rsc[t-1]; hi = rlo[t-1] + (rb[t-1]+1)/rsc[t-1]; }
    float scl = 2047.0f / (hi - lo);
    if (!(hi > lo) || !(scl < 1e37f)){
      if (tid == 0){ s_uT = fkey(lo); s_done = 1; }   // s_fused stays 0 -> fallback
      __syncthreads();
      continue;
    }
    if (t > 0){
      for (int b = tid; b < NB; b += BS) hist[b] = 0u;
      __syncthreads();
    }
    if (t == 0){
      if ((N & 3) == 0){
        int G = N >> 2;
        for (int g = tid; g < G; g += BS){
          float4 v = ((const float4*)sp)[g];
          atomicAdd(&hist[lbin(v.x, lo, scl)], 1u);
          atomicAdd(&hist[lbin(v.y, lo, scl)], 1u);
          atomicAdd(&hist[lbin(v.z, lo, scl)], 1u);
          atomicAdd(&hist[lbin(v.w, lo, scl)], 1u);
        }
      } else {
        for (int i = tid; i < N; i += BS) atomicAdd(&hist[lbin(sp[i], lo, scl)], 1u);
      }
    } else {
      for (int i = tid; i < N; i += BS){
        float sc = sp[i];
        bool act = true;
        for (int q = 0; q < t; ++q) act = act && (lbin(sc, rlo[q], rsc[q]) == rb[q]);
        if (act) atomicAdd(&hist[lbin(sc, lo, scl)], 1u);
      }
    }
    __syncthreads();
    // pick over 2048 bins: lane l owns bins [32l, 32l+32)
    if (tid < 64){
      int l = tid;
      unsigned s = 0;
      for (int q = 0; q < 32; ++q) s += hist[l*32+q];
      unsigned S = s;
      #pragma unroll
      for (int off = 1; off < 64; off <<= 1){
        unsigned u2 = __shfl_down(S, off);
        if (l + off < 64) S += u2;
      }
      unsigned suf = S - s;               // suffix over lanes > l
      unsigned r = (unsigned)s_r;
      int b = -1; unsigned sufnext = 0, cb = 0;
      for (int q = 31; q >= 0; --q){
        unsigned c = hist[l*32+q];
        unsigned nsuf = suf + c;
        if (nsuf >= r && suf < r){ b = l*32+q; sufnext = suf; cb = c; }
        suf = nsuf;
      }
      if (b >= 0){
        rb[t] = b; rlo[t] = lo; rsc[t] = scl;
        s_r = (int)(r - sufnext);
        s_C = (int)cb;
      }
    }
    __syncthreads();
    int C = s_C;
    if (C <= NB){
      // pre-zero the 4x256 radix regions (hist is dead after pick) and reset
      // the compaction counter — all inside the existing barrier window.
      if (tid < 1024) hist[tid] = 0u;
      if (tid == 0) s_cc = 0;
      __syncthreads();
      // compact: candidates (key+idx) AND drop-sum accumulation in one sweep.
      // t==0 fast path: float4 loads, single-bin predicate.
      if (t == 0 && (N & 3) == 0){
        const int b0 = rb[0];
        const float l0 = rlo[0], s0 = rsc[0];
        int G = N >> 2;
        for (int g = tid; g < G; g += BS){
          float4 v = ((const float4*)sp)[g];
          #pragma unroll
          for (int u = 0; u < 4; ++u){
            float sc = (u==0)?v.x:((u==1)?v.y:((u==2)?v.z:v.w));
            int b = lbin(sc, l0, s0);
            if (b == b0){
              int ix = atomicAdd(&s_cc, 1);
              if (ix < NB){ cand[ix] = fkey(sc); candIdx[ix] = (unsigned)(g*4+u); }
            } else if (b < b0){
              int i = g*4+u;
              float m0=0.f,m1=0.f,m2=0.f;
              unsigned w = bm[i>>5];
              if ((w >> (i&31)) & 1u){
                int r = wpfx[i>>5] + __popc(w & ((1u << (i&31)) - 1u));
                m0 = msum[r*3+0]; m1 = msum[r*3+1]; m2 = msum[r*3+2];
              }
              float h0 = h[i*3+0], h1 = h[i*3+1], h2 = h[i*3+2];
              float x0 = fmaxf(m0*Wl[0]+m1*Wl[3]+m2*Wl[6] + bl[0] + h0*Wr[0]+h1*Wr[3]+h2*Wr[6], 0.f);
              float x1 = fmaxf(m0*Wl[1]+m1*Wl[4]+m2*Wl[7] + bl[1] + h0*Wr[1]+h1*Wr[4]+h2*Wr[7], 0.f);
              float x2 = fmaxf(m0*Wl[2]+m1*Wl[5]+m2*Wl[8] + bl[2] + h0*Wr[2]+h1*Wr[5]+h2*Wr[8], 0.f);
              float tt = fast_tanh(sc);
              float gg = fminf(fmaxf(tt*(x0*gw[0]+x1*gw[1]+x2*gw[2]) + gbv, -60.f), 60.f);
              float e = __expf(gg);
              float et = e * tt;
              dl += e; d0 += et*x0; d1 += et*x1; d2 += et*x2;
            }
          }
        }
      } else {
        for (int i = tid; i < N; i += BS){
          float sc = sp[i];
          bool iscand = true, isdrop = false;
          for (int q = 0; q <= t; ++q){
            int b = lbin(sc, rlo[q], rsc[q]);
            if (b != rb[q]){ iscand = false; isdrop = (b < rb[q]); break; }
          }
          if (iscand){
            int ix = atomicAdd(&s_cc, 1);
            if (ix < NB){ cand[ix] = fkey(sc); candIdx[ix] = (unsigned)i; }
          } else if (isdrop){
            float m0=0.f,m1=0.f,m2=0.f;
            unsigned w = bm[i>>5];
            if ((w >> (i&31)) & 1u){
              int r = wpfx[i>>5] + __popc(w & ((1u << (i&31)) - 1u));
              m0 = msum[r*3+0]; m1 = msum[r*3+1]; m2 = msum[r*3+2];
            }
            float h0 = h[i*3+0], h1 = h[i*3+1], h2 = h[i*3+2];
            float x0 = fmaxf(m0*Wl[0]+m1*Wl[3]+m2*Wl[6] + bl[0] + h0*Wr[0]+h1*Wr[3]+h2*Wr[6], 0.f);
            float x1 = fmaxf(m0*Wl[1]+m1*Wl[4]+m2*Wl[7] + bl[1] + h0*Wr[1]+h1*Wr[4]+h2*Wr[7], 0.f);
            float x2 = fmaxf(m0*Wl[2]+m1*Wl[5]+m2*Wl[8] + bl[2] + h0*Wr[2]+h1*Wr[5]+h2*Wr[8], 0.f);
            float tt = fast_tanh(sc);
            float gg = fminf(fmaxf(tt*(x0*gw[0]+x1*gw[1]+x2*gw[2]) + gbv, -60.f), 60.f);
            float e = __expf(gg);
            float et = e * tt;
            dl += e; d0 += et*x0; d1 += et*x1; d2 += et*x2;
          }
        }
      }
      __syncthreads();
      // exact 4-pass radix over cand[0..C), single wave. Each pass uses its own
      // pre-zeroed 256-bin region (hist + pass*256): no in-wave zeroing, one
      // lgkmcnt wait per pass instead of two.
      if (tid < 64){
        int l = tid;
        unsigned pref = 0u, mask = 0u;
        int r = s_r;
        #pragma unroll
        for (int pass = 0; pass < 4; ++pass){
          int shift = 24 - 8*pass;
          unsigned* hp = hist + (pass << 8);
          for (int j = l; j < C; j += 64){
            unsigned u = cand[j];
            if ((u & mask) == pref) atomicAdd(&hp[(u>>shift)&255u], 1u);
          }
          asm volatile("s_waitcnt lgkmcnt(0)" ::: "memory");
          unsigned h0 = hp[4*l+0], h1 = hp[4*l+1], h2 = hp[4*l+2], h3 = hp[4*l+3];
          unsigned ssum = h0+h1+h2+h3;
          unsigned S = ssum;
          #pragma unroll
          for (int off = 1; off < 64; off <<= 1){
            unsigned u2 = __shfl_down(S, off);
            if (l + off < 64) S += u2;
          }
          unsigned Snext = S - ssum;
          unsigned rr = (unsigned)r;
          unsigned suf3 = h3 + Snext;
          unsigned suf2 = h2 + suf3;
          unsigned suf1 = h1 + suf2;
          unsigned suf0 = h0 + suf1;
          int b = -1; unsigned sufn = 0;
          if      (suf3 >= rr && Snext < rr){ b = 4*l+3; sufn = Snext; }
          else if (suf2 >= rr && suf3  < rr){ b = 4*l+2; sufn = suf3; }
          else if (suf1 >= rr && suf2  < rr){ b = 4*l+1; sufn = suf2; }
          else if (suf0 >= rr && suf1  < rr){ b = 4*l+0; sufn = suf1; }
          unsigned long long ball = __ballot(b >= 0);
          int src = __ffsll(ball) - 1;
          b    = __shfl(b, src);
          sufn = (unsigned)__shfl((int)sufn, src);
          pref |= (unsigned)b << shift;
          mask |= 255u << shift;
          r = (int)(rr - sufn);
        }
        if (l == 0) s_uT = pref;
      }
      if (tid == 0){ s_done = 1; s_fused = 1; }
      __syncthreads();
      // candidate fix: subtract in-bucket dropped (key < uT)
      {
        const unsigned uTl = s_uT;
        for (int j = tid; j < C; j += BS){
          if (cand[j] < uTl){
            int i = (int)candIdx[j];
            float sc = sp[i];
            float m0=0.f,m1=0.f,m2=0.f;
            unsigned w = bm[i>>5];
            if ((w >> (i&31)) & 1u){
              int r = wpfx[i>>5] + __popc(w & ((1u << (i&31)) - 1u));
              m0 = msum[r*3+0]; m1 = msum[r*3+1]; m2 = msum[r*3+2];
            }
            float h0 = h[i*3+0], h1 = h[i*3+1], h2 = h[i*3+2];
            float x0 = fmaxf(m0*Wl[0]+m1*Wl[3]+m2*Wl[6] + bl[0] + h0*Wr[0]+h1*Wr[3]+h2*Wr[6], 0.f);
            float x1 = fmaxf(m0*Wl[1]+m1*Wl[4]+m2*Wl[7] + bl[1] + h0*Wr[1]+h1*Wr[4]+h2*Wr[7], 0.f);
            float x2 = fmaxf(m0*Wl[2]+m1*Wl[5]+m2*Wl[8] + bl[2] + h0*Wr[2]+h1*Wr[5]+h2*Wr[8], 0.f);
            float tt = fast_tanh(sc);
            float gg = fminf(fmaxf(tt*(x0*gw[0]+x1*gw[1]+x2*gw[2]) + gbv, -60.f), 60.f);
            float e = __expf(gg);
            float et = e * tt;
            dl += e; d0 += et*x0; d1 += et*x1; d2 += et*x2;
          }
        }
      }
    } else if (t == 2){
      if (tid == 0){ s_uT = fkey(lo + rb[t]/scl); s_done = 1; }  // safety; s_fused=0
      __syncthreads();
    }
  }
  __syncthreads();
  const unsigned uT = s_uT;

  // Fallback correction (rare degenerate paths only): full N sweep
  if (!s_fused){
    for (int i = tid; i < N; i += BS){
      float sc = sp[i];
      if (fkey(sc) < uT){
        float m0=0.f,m1=0.f,m2=0.f;
        unsigned w = bm[i>>5];
        if ((w >> (i&31)) & 1u){
          int r = wpfx[i>>5] + __popc(w & ((1u << (i&31)) - 1u));
          m0 = msum[r*3+0]; m1 = msum[r*3+1]; m2 = msum[r*3+2];
        }
        float h0 = h[i*3+0], h1 = h[i*3+1], h2 = h[i*3+2];
        float x0 = fmaxf(m0*Wl[0]+m1*Wl[3]+m2*Wl[6] + bl[0] + h0*Wr[0]+h1*Wr[3]+h2*Wr[6], 0.f);
        float x1 = fmaxf(m0*Wl[1]+m1*Wl[4]+m2*Wl[7] + bl[1] + h0*Wr[1]+h1*Wr[4]+h2*Wr[7], 0.f);
        float x2 = fmaxf(m0*Wl[2]+m1*Wl[5]+m2*Wl[8] + bl[2] + h0*Wr[2]+h1*Wr[5]+h2*Wr[8], 0.f);
        float tt = fast_tanh(sc);
        float gg = fminf(fmaxf(tt*(x0*gw[0]+x1*gw[1]+x2*gw[2]) + gbv, -60.f), 60.f);
        float e = __expf(gg);
        float et = e * tt;
        dl += e; d0 += et*x0; d1 += et*x1; d2 += et*x2;
      }
    }
  }
  #pragma unroll
  for (int off = 32; off > 0; off >>= 1){
    dl += __shfl_down(dl, off); d0 += __shfl_down(d0, off);
    d1 += __shfl_down(d1, off); d2 += __shfl_down(d2, off);
  }
  if ((tid & 63) == 0){
    int w = tid >> 6;
    wredB[w*4+0]=dl; wredB[w*4+1]=d0; wredB[w*4+2]=d1; wredB[w*4+3]=d2;
  }
  __syncthreads();
  if (tid == 0){
    float L=0.f, A0=0.f, A1=0.f, A2=0.f;
    for (int w = 0; w < BS/64; ++w){
      L  += wredA[w*4+0] - wredB[w*4+0];
      A0 += wredA[w*4+1] - wredB[w*4+1];
      A1 += wredA[w*4+2] - wredB[w*4+2];
      A2 += wredA[w*4+3] - wredB[w*4+3];
    }
    float inv = 1.f / L;
    float r0 = fmaxf(A0*inv, 0.f);
    float r1 = fmaxf(A1*inv, 0.f);
    float r2 = fmaxf(A2*inv, 0.f);
    float rr = fmaxf(r0*linW[0] + r1*linW[1] + r2*linW[2] + linb[0], 0.f);
    atomicAdd(acc, rr * mlpW[p]);            // relu(relu(x)) == relu(x)
    __threadfence();
    unsigned old = atomicAdd(counter, 1u);
    if (old == (unsigned)(P-1)){
      __threadfence();
      float z = atomicAdd(acc, 0.f) + mlpb[0];   // atomic read: full sum visible
      float a = 1.f / (1.f + expf(-z));
      unsigned A = __float_as_uint(a);
      unsigned B = (A + 0x7FFFu + ((A >> 16) & 1u)) >> 16;   // bf16 RNE bits
      out[0] = (A & 0xFFFF0000u) | (B & 0xFFFFu);            // dual-format store
    }
  }
}

// ================= launcher: 3 dispatches =================
extern "C" void kernel_launch(void* const* d_in, const int* in_sizes, int n_in,
                              void* d_out, int out_size, void* d_ws, size_t ws_size,
                              hipStream_t stream){
  const float* x      = (const float*)d_in[0];
  const int*   ei     = (const int*)  d_in[1];
  const int*   pe     = (const int*)  d_in[2];
  const float* W_pool = (const float*)d_in[3];
  const float* b_pool = (const float*)d_in[4];
  const float* W_self = (const float*)d_in[5];
  const float* W_neigh= (const float*)d_in[6];
  const float* b_conv = (const float*)d_in[7];
  const float* sWl    = (const float*)d_in[8];
  const float* sbl    = (const float*)d_in[9];
  const float* sWr    = (const float*)d_in[10];
  const float* pWrel  = (const float*)d_in[11];
  const float* pWroot = (const float*)d_in[12];
  const float* pB     = (const float*)d_in[13];
  const float* gW     = (const float*)d_in[14];
  const float* gB     = (const float*)d_in[15];
  const float* linW   = (const float*)d_in[16];
  const float* linb   = (const float*)d_in[17];
  const float* mlpW   = (const float*)d_in[18];
  const float* mlpb   = (const float*)d_in[19];

  const int N  = in_sizes[0] / 3;
  const int E  = in_sizes[1] / 2;
  const int P  = in_sizes[13];
  const int EP = in_sizes[2] / (2 * P);
  const int K  = (4*N + 4) / 5;          // ceil(0.8*N)

  // ws layout (float elements): [0]=acc, [1]=counter, pad; [16,16+3N)=agg/h; sp after.
  float*    ws      = (float*)d_ws;
  float*    acc     = ws;
  unsigned* counter = (unsigned*)(ws + 1);
  float*    agg     = ws + 16;           // becomes h in-place after k_h2
  float*    h       = agg;
  float*    spG     = ws + 16 + (size_t)3*N;

  k_edge<<<(E+255)/256, 256, 0, stream>>>(x, ei, W_pool, b_pool, agg, acc, counter, E);
  k_h2  <<<(N+255)/256, 256, 0, stream>>>(x, agg, W_pool, b_pool,
                                          W_self, W_neigh, b_conv, N);
  k_mega<<<P, BS, 0, stream>>>(h, pe, sWl, sbl, sWr, pWrel, pWroot, pB, gW, gB,
                               linW, linb, mlpW, mlpb,
                               spG, acc, counter, (unsigned*)d_out, N, EP, K, P);
}

// Round 8
// 234.685 us; speedup vs baseline: 1.1008x; 1.0243x over previous
//
#include <hip/hip_runtime.h>
#include <math.h>

#define MAXM 2048          // >= max distinct dst nodes per pathway (<= EP=2000)
#define BMW  640           // bitmap words: supports N <= 20480
#define BS   1024          // mega block size (16 waves; VGPR<=64 => 2 blocks/CU)
#define NB   2048          // linear hist bins == candidate cap

// monotonic float -> uint key (larger float => larger uint)
__device__ __forceinline__ unsigned fkey(float f){
  unsigned u = __float_as_uint(f);
  return (u & 0x80000000u) ? ~u : (u | 0x80000000u);
}
__device__ __forceinline__ int lbin(float sc, float lo, float scl){
  int b = (int)((sc - lo) * scl);
  return b < 0 ? 0 : (b > NB-1 ? NB-1 : b);
}
// fast tanh via native exp+rcp: 1 - 2/(e^{2x}+1). Only for GATE values
// (softmax-ratio path) — never for selection keys.
__device__ __forceinline__ float fast_tanh(float x){
  float e = __expf(2.f*x);
  return 1.f - 2.f*__builtin_amdgcn_rcpf(e + 1.f);
}
__device__ __forceinline__ void hp_eval(const float* __restrict__ x, int i,
                                        const float* __restrict__ Wp,
                                        const float* __restrict__ bp, float* o){
  float x0 = x[i*3+0], x1 = x[i*3+1], x2 = x[i*3+2];
  #pragma unroll
  for (int j = 0; j < 3; ++j)
    o[j] = fmaxf(x0*Wp[0*3+j] + x1*Wp[1*3+j] + x2*Wp[2*3+j] + bp[j], 0.f);
}

// K1: agg[d] = max(agg[d], hp[s]) — agg now PADDED to stride 4 (16B aligned)
// so k_mega can read h as one dwordx4. Poison (negative) loses to hp>=0.
__global__ void k_edge(const float* __restrict__ x, const int* __restrict__ ei,
                       const float* __restrict__ Wp, const float* __restrict__ bp,
                       float* __restrict__ agg, float* __restrict__ acc,
                       unsigned* __restrict__ counter, int E){
  if (blockIdx.x == 0 && threadIdx.x == 0){ acc[0] = 0.f; counter[0] = 0u; }
  int e = blockIdx.x*blockDim.x + threadIdx.x;
  if (e >= E) return;
  int s = ei[e], d = ei[E+e];
  float o[3]; hp_eval(x, s, Wp, bp, o);
  #pragma unroll
  for (int j = 0; j < 3; ++j)
    if (o[j] > 0.f && o[j] > agg[d*4+j])
      atomicMax((int*)&agg[d*4+j], __float_as_int(o[j]));
}

// K2: h_i = tanh(x@Ws + max(agg_i, hp_i)@Wn + bc), in-place over padded agg.
// Writes lane 3 = 0 so k_mega's dwordx4 reads are defined. libm tanhf kept.
__global__ void k_h2(const float* __restrict__ x, float* __restrict__ hb,
                     const float* __restrict__ Wp, const float* __restrict__ bp,
                     const float* __restrict__ Ws, const float* __restrict__ Wn,
                     const float* __restrict__ bc, int N){
  int i = blockIdx.x*blockDim.x + threadIdx.x;
  if (i >= N) return;
  float hp[3]; hp_eval(x, i, Wp, bp, hp);
  float x0 = x[i*3+0], x1 = x[i*3+1], x2 = x[i*3+2];
  float a0 = fmaxf(hb[i*4+0], hp[0]);
  float a1 = fmaxf(hb[i*4+1], hp[1]);
  float a2 = fmaxf(hb[i*4+2], hp[2]);
  float o[3];
  #pragma unroll
  for (int j = 0; j < 3; ++j){
    float v = x0*Ws[0*3+j] + x1*Ws[1*3+j] + x2*Ws[2*3+j]
            + a0*Wn[0*3+j] + a1*Wn[1*3+j] + a2*Wn[2*3+j] + bc[j];
    o[j] = tanhf(v);
  }
  float4 hv; hv.x = o[0]; hv.y = o[1]; hv.z = o[2]; hv.w = 0.f;
  *reinterpret_cast<float4*>(&hb[i*4]) = hv;
}

// K_mega: one 1024-thr block per pathway (grid=P=300; 2 blocks/CU co-resident).
// h is [N][4] (dwordx4 loads); msum is [MAXM][4] in LDS (ds_read_b128).
// Structure identical to R7 otherwise; selection bit-exact.
__global__ void __launch_bounds__(BS)
k_mega(const float* __restrict__ h, const int* __restrict__ pe,
       const float* __restrict__ sWl, const float* __restrict__ sbl, const float* __restrict__ sWr,
       const float* __restrict__ pWrel, const float* __restrict__ pWroot, const float* __restrict__ pB,
       const float* __restrict__ gW, const float* __restrict__ gB,
       const float* __restrict__ linW, const float* __restrict__ linb,
       const float* __restrict__ mlpW, const float* __restrict__ mlpb,
       float* __restrict__ spG, float* __restrict__ acc, unsigned* __restrict__ counter,
       unsigned* __restrict__ out, int N, int EP, int K, int P){
  __shared__ unsigned bm[BMW];
  __shared__ int      wpfx[BMW];
  __shared__ float    msum[MAXM*4];   // stride-4: ds_read_b128 per rank
  __shared__ unsigned scrA[NB];       // cnt -> hist (2048 bins / 4x256-bin radix)
  __shared__ unsigned scrB[NB];       // adot -> cand keys
  __shared__ unsigned candIdx[NB];    // candidate node indices
  __shared__ float    wredf[(BS/64)*2];
  __shared__ float    wredA[(BS/64)*4];
  __shared__ float    wredB[(BS/64)*4];
  __shared__ float    s_mn, s_mx;
  __shared__ float    rlo[3], rsc[3];
  __shared__ int      rb[3];
  __shared__ int      s_r, s_C, s_cc, s_done, s_fused;
  __shared__ unsigned s_uT;

  const int p = blockIdx.x;
  const int tid = threadIdx.x;

  float Wl[9], Wr[9], bl[3], wrel[3], wroot[3], gw[3];
  #pragma unroll
  for (int j = 0; j < 9; ++j){ Wl[j] = sWl[p*9+j]; Wr[j] = sWr[p*9+j]; }
  #pragma unroll
  for (int j = 0; j < 3; ++j){
    bl[j] = sbl[p*3+j]; wrel[j] = pWrel[p*3+j];
    wroot[j] = pWroot[p*3+j]; gw[j] = gW[p*3+j];
  }
  float pbv = pB[p], gbv = gB[p];
  float* sp = spG + (size_t)p*N;

  int*   cnt  = (int*)scrA;
  float* adot = (float*)scrB;

  for (int s = tid; s < MAXM; s += BS){
    cnt[s] = 0; adot[s] = 0.f;
    float4 z; z.x = 0.f; z.y = 0.f; z.z = 0.f; z.w = 0.f;
    *reinterpret_cast<float4*>(&msum[s*4]) = z;
  }
  for (int s = tid; s < BMW; s += BS) bm[s] = 0u;
  if (tid == 0){ s_done = 0; s_fused = 0; s_uT = 0u; }
  __syncthreads();

  const int* ps = pe + (size_t)p*2*EP;
  const int* pd = ps + EP;

  // A1: mark dst nodes
  for (int e = tid; e < EP; e += BS) atomicOr(&bm[pd[e]>>5], 1u << (pd[e]&31));
  __syncthreads();
  // A2: popcount + exclusive prefix (single-wave shfl scan)
  if (tid < 64){
    int l = tid, base = l*10;
    int c[10], s = 0;
    #pragma unroll
    for (int q = 0; q < 10; ++q){ c[q] = __popc(bm[base+q]); s += c[q]; }
    int pre = s;
    #pragma unroll
    for (int off = 1; off < 64; off <<= 1){
      int t = __shfl_up(pre, off);
      if (l >= off) pre += t;
    }
    pre -= s;
    #pragma unroll
    for (int q = 0; q < 10; ++q){ wpfx[base+q] = pre; pre += c[q]; }
  }
  __syncthreads();
  // A3: msum/cnt keyed by rank(dst); h read as dwordx4
  for (int e = tid; e < EP; e += BS){
    int s = ps[e], d = pd[e];
    int r = wpfx[d>>5] + __popc(bm[d>>5] & ((1u << (d&31)) - 1u));
    float4 hs = *reinterpret_cast<const float4*>(&h[s*4]);
    atomicAdd(&cnt[r], 1);
    atomicAdd(&msum[r*4+0], hs.x);
    atomicAdd(&msum[r*4+1], hs.y);
    atomicAdd(&msum[r*4+2], hs.z);
  }
  __syncthreads();
  // A4: msum -> mean; re-zero cnt (cnt==hist storage => t==0 hist pre-zeroed)
  for (int r = tid; r < MAXM; r += BS){
    int c = cnt[r];
    cnt[r] = 0;
    if (c > 0){
      float inv = 1.f / (float)c;
      msum[r*4+0] *= inv; msum[r*4+1] *= inv; msum[r*4+2] *= inv;
    }
  }
  __syncthreads();
  // A5: adot[rank(d)] += xc(s) . wrel
  for (int e = tid; e < EP; e += BS){
    int s = ps[e], d = pd[e];
    float m0=0.f,m1=0.f,m2=0.f;
    unsigned w = bm[s>>5];
    if ((w >> (s&31)) & 1u){
      int rs = wpfx[s>>5] + __popc(w & ((1u << (s&31)) - 1u));
      float4 mv = *reinterpret_cast<const float4*>(&msum[rs*4]);
      m0 = mv.x; m1 = mv.y; m2 = mv.z;
    }
    float4 hv = *reinterpret_cast<const float4*>(&h[s*4]);
    float h0 = hv.x, h1 = hv.y, h2 = hv.z;
    float x0 = fmaxf(m0*Wl[0]+m1*Wl[3]+m2*Wl[6] + bl[0] + h0*Wr[0]+h1*Wr[3]+h2*Wr[6], 0.f);
    float x1 = fmaxf(m0*Wl[1]+m1*Wl[4]+m2*Wl[7] + bl[1] + h0*Wr[1]+h1*Wr[4]+h2*Wr[7], 0.f);
    float x2 = fmaxf(m0*Wl[2]+m1*Wl[5]+m2*Wl[8] + bl[2] + h0*Wr[2]+h1*Wr[5]+h2*Wr[8], 0.f);
    int rd = wpfx[d>>5] + __popc(bm[d>>5] & ((1u << (d&31)) - 1u));
    atomicAdd(&adot[rd], x0*wrel[0] + x1*wrel[1] + x2*wrel[2]);
  }
  __syncthreads();

  // B: fused sweep — score -> sp, min/max, gate totals over ALL nodes
  float mn = 3.0e38f, mx = -3.0e38f;
  float tl = 0.f, ta0 = 0.f, ta1 = 0.f, ta2 = 0.f;
  for (int i = tid; i < N; i += BS){
    float m0=0.f,m1=0.f,m2=0.f,ad=0.f;
    unsigned w = bm[i>>5];
    if ((w >> (i&31)) & 1u){
      int r = wpfx[i>>5] + __popc(w & ((1u << (i&31)) - 1u));
      float4 mv = *reinterpret_cast<const float4*>(&msum[r*4]);
      m0 = mv.x; m1 = mv.y; m2 = mv.z;
      ad = adot[r];
    }
    float4 hv = *reinterpret_cast<const float4*>(&h[i*4]);
    float h0 = hv.x, h1 = hv.y, h2 = hv.z;
    float x0 = fmaxf(m0*Wl[0]+m1*Wl[3]+m2*Wl[6] + bl[0] + h0*Wr[0]+h1*Wr[3]+h2*Wr[6], 0.f);
    float x1 = fmaxf(m0*Wl[1]+m1*Wl[4]+m2*Wl[7] + bl[1] + h0*Wr[1]+h1*Wr[4]+h2*Wr[7], 0.f);
    float x2 = fmaxf(m0*Wl[2]+m1*Wl[5]+m2*Wl[8] + bl[2] + h0*Wr[2]+h1*Wr[5]+h2*Wr[8], 0.f);
    float sc = ad + x0*wroot[0]+x1*wroot[1]+x2*wroot[2] + pbv;
    sp[i] = sc;
    mn = fminf(mn, sc); mx = fmaxf(mx, sc);
    float tt = fast_tanh(sc);
    float g = fminf(fmaxf(tt*(x0*gw[0]+x1*gw[1]+x2*gw[2]) + gbv, -60.f), 60.f);
    float e = __expf(g);
    float et = e * tt;
    tl += e; ta0 += et*x0; ta1 += et*x1; ta2 += et*x2;
  }
  #pragma unroll
  for (int off = 32; off > 0; off >>= 1){
    mn  = fminf(mn, __shfl_down(mn, off));
    mx  = fmaxf(mx, __shfl_down(mx, off));
    tl  += __shfl_down(tl,  off); ta0 += __shfl_down(ta0, off);
    ta1 += __shfl_down(ta1, off); ta2 += __shfl_down(ta2, off);
  }
  if ((tid & 63) == 0){
    int w = tid >> 6;
    wredf[w*2+0] = mn; wredf[w*2+1] = mx;
    wredA[w*4+0]=tl; wredA[w*4+1]=ta0; wredA[w*4+2]=ta1; wredA[w*4+3]=ta2;
  }
  __syncthreads();
  if (tid == 0){
    float a = 3.0e38f, b = -3.0e38f;
    for (int w = 0; w < BS/64; ++w){ a = fminf(a, wredf[w*2+0]); b = fmaxf(b, wredf[w*2+1]); }
    s_mn = a; s_mx = b; s_r = K;
    if (!(b > a)){ s_uT = fkey(a); s_done = 1; s_fused = 1; }  // all equal: none dropped
  }
  __syncthreads();

  unsigned* hist = scrA;    // overlays cnt (dead; pre-zeroed by A4 for t==0)
  unsigned* cand = scrB;    // overlays adot (dead; gate math needs only msum)

  float dl = 0.f, d0 = 0.f, d1 = 0.f, d2 = 0.f;   // drop-sum registers

  for (int t = 0; t < 3; ++t){
    __syncthreads();
    if (s_done) break;
    float lo, hi;
    if (t == 0){ lo = s_mn; hi = s_mx; }
    else { lo = rlo[t-1] + rb[t-1]/rsc[t-1]; hi = rlo[t-1] + (rb[t-1]+1)/rsc[t-1]; }
    float scl = 2047.0f / (hi - lo);
    if (!(hi > lo) || !(scl < 1e37f)){
      if (tid == 0){ s_uT = fkey(lo); s_done = 1; }   // s_fused stays 0 -> fallback
      __syncthreads();
      continue;
    }
    if (t > 0){
      for (int b = tid; b < NB; b += BS) hist[b] = 0u;
      __syncthreads();
    }
    if (t == 0){
      if ((N & 3) == 0){
        int G = N >> 2;
        for (int g = tid; g < G; g += BS){
          float4 v = ((const float4*)sp)[g];
          atomicAdd(&hist[lbin(v.x, lo, scl)], 1u);
          atomicAdd(&hist[lbin(v.y, lo, scl)], 1u);
          atomicAdd(&hist[lbin(v.z, lo, scl)], 1u);
          atomicAdd(&hist[lbin(v.w, lo, scl)], 1u);
        }
      } else {
        for (int i = tid; i < N; i += BS) atomicAdd(&hist[lbin(sp[i], lo, scl)], 1u);
      }
    } else {
      for (int i = tid; i < N; i += BS){
        float sc = sp[i];
        bool act = true;
        for (int q = 0; q < t; ++q) act = act && (lbin(sc, rlo[q], rsc[q]) == rb[q]);
        if (act) atomicAdd(&hist[lbin(sc, lo, scl)], 1u);
      }
    }
    __syncthreads();
    // pick over 2048 bins: lane l owns bins [32l, 32l+32)
    if (tid < 64){
      int l = tid;
      unsigned s = 0;
      for (int q = 0; q < 32; ++q) s += hist[l*32+q];
      unsigned S = s;
      #pragma unroll
      for (int off = 1; off < 64; off <<= 1){
        unsigned u2 = __shfl_down(S, off);
        if (l + off < 64) S += u2;
      }
      unsigned suf = S - s;               // suffix over lanes > l
      unsigned r = (unsigned)s_r;
      int b = -1; unsigned sufnext = 0, cb = 0;
      for (int q = 31; q >= 0; --q){
        unsigned c = hist[l*32+q];
        unsigned nsuf = suf + c;
        if (nsuf >= r && suf < r){ b = l*32+q; sufnext = suf; cb = c; }
        suf = nsuf;
      }
      if (b >= 0){
        rb[t] = b; rlo[t] = lo; rsc[t] = scl;
        s_r = (int)(r - sufnext);
        s_C = (int)cb;
      }
    }
    __syncthreads();
    int C = s_C;
    if (C <= NB){
      // pre-zero the 4x256 radix regions (hist is dead after pick) and reset
      // the compaction counter — all inside the existing barrier window.
      if (tid < 1024) hist[tid] = 0u;
      if (tid == 0) s_cc = 0;
      __syncthreads();
      // compact: candidates (key+idx) AND drop-sum accumulation in one sweep.
      // t==0 fast path: float4 loads, single-bin predicate.
      if (t == 0 && (N & 3) == 0){
        const int b0 = rb[0];
        const float l0 = rlo[0], s0 = rsc[0];
        int G = N >> 2;
        for (int g = tid; g < G; g += BS){
          float4 v = ((const float4*)sp)[g];
          #pragma unroll
          for (int u = 0; u < 4; ++u){
            float sc = (u==0)?v.x:((u==1)?v.y:((u==2)?v.z:v.w));
            int b = lbin(sc, l0, s0);
            if (b == b0){
              int ix = atomicAdd(&s_cc, 1);
              if (ix < NB){ cand[ix] = fkey(sc); candIdx[ix] = (unsigned)(g*4+u); }
            } else if (b < b0){
              int i = g*4+u;
              float m0=0.f,m1=0.f,m2=0.f;
              unsigned w = bm[i>>5];
              if ((w >> (i&31)) & 1u){
                int r = wpfx[i>>5] + __popc(w & ((1u << (i&31)) - 1u));
                float4 mv = *reinterpret_cast<const float4*>(&msum[r*4]);
                m0 = mv.x; m1 = mv.y; m2 = mv.z;
              }
              float4 hv = *reinterpret_cast<const float4*>(&h[i*4]);
              float h0 = hv.x, h1 = hv.y, h2 = hv.z;
              float x0 = fmaxf(m0*Wl[0]+m1*Wl[3]+m2*Wl[6] + bl[0] + h0*Wr[0]+h1*Wr[3]+h2*Wr[6], 0.f);
              float x1 = fmaxf(m0*Wl[1]+m1*Wl[4]+m2*Wl[7] + bl[1] + h0*Wr[1]+h1*Wr[4]+h2*Wr[7], 0.f);
              float x2 = fmaxf(m0*Wl[2]+m1*Wl[5]+m2*Wl[8] + bl[2] + h0*Wr[2]+h1*Wr[5]+h2*Wr[8], 0.f);
              float tt = fast_tanh(sc);
              float gg = fminf(fmaxf(tt*(x0*gw[0]+x1*gw[1]+x2*gw[2]) + gbv, -60.f), 60.f);
              float e = __expf(gg);
              float et = e * tt;
              dl += e; d0 += et*x0; d1 += et*x1; d2 += et*x2;
            }
          }
        }
      } else {
        for (int i = tid; i < N; i += BS){
          float sc = sp[i];
          bool iscand = true, isdrop = false;
          for (int q = 0; q <= t; ++q){
            int b = lbin(sc, rlo[q], rsc[q]);
            if (b != rb[q]){ iscand = false; isdrop = (b < rb[q]); break; }
          }
          if (iscand){
            int ix = atomicAdd(&s_cc, 1);
            if (ix < NB){ cand[ix] = fkey(sc); candIdx[ix] = (unsigned)i; }
          } else if (isdrop){
            float m0=0.f,m1=0.f,m2=0.f;
            unsigned w = bm[i>>5];
            if ((w >> (i&31)) & 1u){
              int r = wpfx[i>>5] + __popc(w & ((1u << (i&31)) - 1u));
              float4 mv = *reinterpret_cast<const float4*>(&msum[r*4]);
              m0 = mv.x; m1 = mv.y; m2 = mv.z;
            }
            float4 hv = *reinterpret_cast<const float4*>(&h[i*4]);
            float h0 = hv.x, h1 = hv.y, h2 = hv.z;
            float x0 = fmaxf(m0*Wl[0]+m1*Wl[3]+m2*Wl[6] + bl[0] + h0*Wr[0]+h1*Wr[3]+h2*Wr[6], 0.f);
            float x1 = fmaxf(m0*Wl[1]+m1*Wl[4]+m2*Wl[7] + bl[1] + h0*Wr[1]+h1*Wr[4]+h2*Wr[7], 0.f);
            float x2 = fmaxf(m0*Wl[2]+m1*Wl[5]+m2*Wl[8] + bl[2] + h0*Wr[2]+h1*Wr[5]+h2*Wr[8], 0.f);
            float tt = fast_tanh(sc);
            float gg = fminf(fmaxf(tt*(x0*gw[0]+x1*gw[1]+x2*gw[2]) + gbv, -60.f), 60.f);
            float e = __expf(gg);
            float et = e * tt;
            dl += e; d0 += et*x0; d1 += et*x1; d2 += et*x2;
          }
        }
      }
      __syncthreads();
      // exact 4-pass radix over cand[0..C), single wave, pre-zeroed regions
      if (tid < 64){
        int l = tid;
        unsigned pref = 0u, mask = 0u;
        int r = s_r;
        #pragma unroll
        for (int pass = 0; pass < 4; ++pass){
          int shift = 24 - 8*pass;
          unsigned* hp = hist + (pass << 8);
          for (int j = l; j < C; j += 64){
            unsigned u = cand[j];
            if ((u & mask) == pref) atomicAdd(&hp[(u>>shift)&255u], 1u);
          }
          asm volatile("s_waitcnt lgkmcnt(0)" ::: "memory");
          unsigned h0 = hp[4*l+0], h1 = hp[4*l+1], h2 = hp[4*l+2], h3 = hp[4*l+3];
          unsigned ssum = h0+h1+h2+h3;
          unsigned S = ssum;
          #pragma unroll
          for (int off = 1; off < 64; off <<= 1){
            unsigned u2 = __shfl_down(S, off);
            if (l + off < 64) S += u2;
          }
          unsigned Snext = S - ssum;
          unsigned rr = (unsigned)r;
          unsigned suf3 = h3 + Snext;
          unsigned suf2 = h2 + suf3;
          unsigned suf1 = h1 + suf2;
          unsigned suf0 = h0 + suf1;
          int b = -1; unsigned sufn = 0;
          if      (suf3 >= rr && Snext < rr){ b = 4*l+3; sufn = Snext; }
          else if (suf2 >= rr && suf3  < rr){ b = 4*l+2; sufn = suf3; }
          else if (suf1 >= rr && suf2  < rr){ b = 4*l+1; sufn = suf2; }
          else if (suf0 >= rr && suf1  < rr){ b = 4*l+0; sufn = suf1; }
          unsigned long long ball = __ballot(b >= 0);
          int src = __ffsll(ball) - 1;
          b    = __shfl(b, src);
          sufn = (unsigned)__shfl((int)sufn, src);
          pref |= (unsigned)b << shift;
          mask |= 255u << shift;
          r = (int)(rr - sufn);
        }
        if (l == 0) s_uT = pref;
      }
      if (tid == 0){ s_done = 1; s_fused = 1; }
      __syncthreads();
      // candidate fix: subtract in-bucket dropped (key < uT)
      {
        const unsigned uTl = s_uT;
        for (int j = tid; j < C; j += BS){
          if (cand[j] < uTl){
            int i = (int)candIdx[j];
            float sc = sp[i];
            float m0=0.f,m1=0.f,m2=0.f;
            unsigned w = bm[i>>5];
            if ((w >> (i&31)) & 1u){
              int r = wpfx[i>>5] + __popc(w & ((1u << (i&31)) - 1u));
              float4 mv = *reinterpret_cast<const float4*>(&msum[r*4]);
              m0 = mv.x; m1 = mv.y; m2 = mv.z;
            }
            float4 hv = *reinterpret_cast<const float4*>(&h[i*4]);
            float h0 = hv.x, h1 = hv.y, h2 = hv.z;
            float x0 = fmaxf(m0*Wl[0]+m1*Wl[3]+m2*Wl[6] + bl[0] + h0*Wr[0]+h1*Wr[3]+h2*Wr[6], 0.f);
            float x1 = fmaxf(m0*Wl[1]+m1*Wl[4]+m2*Wl[7] + bl[1] + h0*Wr[1]+h1*Wr[4]+h2*Wr[7], 0.f);
            float x2 = fmaxf(m0*Wl[2]+m1*Wl[5]+m2*Wl[8] + bl[2] + h0*Wr[2]+h1*Wr[5]+h2*Wr[8], 0.f);
            float tt = fast_tanh(sc);
            float gg = fminf(fmaxf(tt*(x0*gw[0]+x1*gw[1]+x2*gw[2]) + gbv, -60.f), 60.f);
            float e = __expf(gg);
            float et = e * tt;
            dl += e; d0 += et*x0; d1 += et*x1; d2 += et*x2;
          }
        }
      }
    } else if (t == 2){
      if (tid == 0){ s_uT = fkey(lo + rb[t]/scl); s_done = 1; }  // safety; s_fused=0
      __syncthreads();
    }
  }
  __syncthreads();
  const unsigned uT = s_uT;

  // Fallback correction (rare degenerate paths only): full N sweep
  if (!s_fused){
    for (int i = tid; i < N; i += BS){
      float sc = sp[i];
      if (fkey(sc) < uT){
        float m0=0.f,m1=0.f,m2=0.f;
        unsigned w = bm[i>>5];
        if ((w >> (i&31)) & 1u){
          int r = wpfx[i>>5] + __popc(w & ((1u << (i&31)) - 1u));
          float4 mv = *reinterpret_cast<const float4*>(&msum[r*4]);
          m0 = mv.x; m1 = mv.y; m2 = mv.z;
        }
        float4 hv = *reinterpret_cast<const float4*>(&h[i*4]);
        float h0 = hv.x, h1 = hv.y, h2 = hv.z;
        float x0 = fmaxf(m0*Wl[0]+m1*Wl[3]+m2*Wl[6] + bl[0] + h0*Wr[0]+h1*Wr[3]+h2*Wr[6], 0.f);
        float x1 = fmaxf(m0*Wl[1]+m1*Wl[4]+m2*Wl[7] + bl[1] + h0*Wr[1]+h1*Wr[4]+h2*Wr[7], 0.f);
        float x2 = fmaxf(m0*Wl[2]+m1*Wl[5]+m2*Wl[8] + bl[2] + h0*Wr[2]+h1*Wr[5]+h2*Wr[8], 0.f);
        float tt = fast_tanh(sc);
        float gg = fminf(fmaxf(tt*(x0*gw[0]+x1*gw[1]+x2*gw[2]) + gbv, -60.f), 60.f);
        float e = __expf(gg);
        float et = e * tt;
        dl += e; d0 += et*x0; d1 += et*x1; d2 += et*x2;
      }
    }
  }
  #pragma unroll
  for (int off = 32; off > 0; off >>= 1){
    dl += __shfl_down(dl, off); d0 += __shfl_down(d0, off);
    d1 += __shfl_down(d1, off); d2 += __shfl_down(d2, off);
  }
  if ((tid & 63) == 0){
    int w = tid >> 6;
    wredB[w*4+0]=dl; wredB[w*4+1]=d0; wredB[w*4+2]=d1; wredB[w*4+3]=d2;
  }
  __syncthreads();
  if (tid == 0){
    float L=0.f, A0=0.f, A1=0.f, A2=0.f;
    for (int w = 0; w < BS/64; ++w){
      L  += wredA[w*4+0] - wredB[w*4+0];
      A0 += wredA[w*4+1] - wredB[w*4+1];
      A1 += wredA[w*4+2] - wredB[w*4+2];
      A2 += wredA[w*4+3] - wredB[w*4+3];
    }
    float inv = 1.f / L;
    float r0 = fmaxf(A0*inv, 0.f);
    float r1 = fmaxf(A1*inv, 0.f);
    float r2 = fmaxf(A2*inv, 0.f);
    float rr = fmaxf(r0*linW[0] + r1*linW[1] + r2*linW[2] + linb[0], 0.f);
    atomicAdd(acc, rr * mlpW[p]);            // relu(relu(x)) == relu(x)
    __threadfence();
    unsigned old = atomicAdd(counter, 1u);
    if (old == (unsigned)(P-1)){
      __threadfence();
      float z = atomicAdd(acc, 0.f) + mlpb[0];   // atomic read: full sum visible
      float a = 1.f / (1.f + expf(-z));
      unsigned A = __float_as_uint(a);
      unsigned B = (A + 0x7FFFu + ((A >> 16) & 1u)) >> 16;   // bf16 RNE bits
      out[0] = (A & 0xFFFF0000u) | (B & 0xFFFFu);            // dual-format store
    }
  }
}

// ================= launcher: 3 dispatches =================
extern "C" void kernel_launch(void* const* d_in, const int* in_sizes, int n_in,
                              void* d_out, int out_size, void* d_ws, size_t ws_size,
                              hipStream_t stream){
  const float* x      = (const float*)d_in[0];
  const int*   ei     = (const int*)  d_in[1];
  const int*   pe     = (const int*)  d_in[2];
  const float* W_pool = (const float*)d_in[3];
  const float* b_pool = (const float*)d_in[4];
  const float* W_self = (const float*)d_in[5];
  const float* W_neigh= (const float*)d_in[6];
  const float* b_conv = (const float*)d_in[7];
  const float* sWl    = (const float*)d_in[8];
  const float* sbl    = (const float*)d_in[9];
  const float* sWr    = (const float*)d_in[10];
  const float* pWrel  = (const float*)d_in[11];
  const float* pWroot = (const float*)d_in[12];
  const float* pB     = (const float*)d_in[13];
  const float* gW     = (const float*)d_in[14];
  const float* gB     = (const float*)d_in[15];
  const float* linW   = (const float*)d_in[16];
  const float* linb   = (const float*)d_in[17];
  const float* mlpW   = (const float*)d_in[18];
  const float* mlpb   = (const float*)d_in[19];

  const int N  = in_sizes[0] / 3;
  const int E  = in_sizes[1] / 2;
  const int P  = in_sizes[13];
  const int EP = in_sizes[2] / (2 * P);
  const int K  = (4*N + 4) / 5;          // ceil(0.8*N)

  // ws layout (float elements): [0]=acc, [1]=counter, pad;
  // [16,16+4N)=agg/h (PADDED stride-4, 16B aligned); sp after.
  // need = (16 + 4N + P*N)*4 ≈ 24.3 MB; proven available (>= 35.7 MB used before)
  float*    ws      = (float*)d_ws;
  float*    acc     = ws;
  unsigned* counter = (unsigned*)(ws + 1);
  float*    agg     = ws + 16;           // becomes h in-place after k_h2
  float*    h       = agg;
  float*    spG     = ws + 16 + (size_t)4*N;

  k_edge<<<(E+255)/256, 256, 0, stream>>>(x, ei, W_pool, b_pool, agg, acc, counter, E);
  k_h2  <<<(N+255)/256, 256, 0, stream>>>(x, agg, W_pool, b_pool,
                                          W_self, W_neigh, b_conv, N);
  k_mega<<<P, BS, 0, stream>>>(h, pe, sWl, sbl, sWr, pWrel, pWroot, pB, gW, gB,
                               linW, linb, mlpW, mlpb,
                               spG, acc, counter, (unsigned*)d_out, N, EP, K, P);
}

// Round 9
// 228.714 us; speedup vs baseline: 1.1295x; 1.0261x over previous
//
#include <hip/hip_runtime.h>
#include <math.h>

#define MAXM 2048          // >= max distinct dst nodes per pathway (<= EP=2000)
#define BMW  640           // bitmap words: supports N <= 20480
#define BS   1024          // mega block size (16 waves; VGPR<=64 => 2 blocks/CU)
#define NB   2048          // linear hist bins == candidate cap

// monotonic float -> uint key (larger float => larger uint)
__device__ __forceinline__ unsigned fkey(float f){
  unsigned u = __float_as_uint(f);
  return (u & 0x80000000u) ? ~u : (u | 0x80000000u);
}
__device__ __forceinline__ int lbin(float sc, float lo, float scl){
  int b = (int)((sc - lo) * scl);
  return b < 0 ? 0 : (b > NB-1 ? NB-1 : b);
}
// fast tanh via native exp+rcp: 1 - 2/(e^{2x}+1). Only for GATE values
// (softmax-ratio path) — never for selection keys.
__device__ __forceinline__ float fast_tanh(float x){
  float e = __expf(2.f*x);
  return 1.f - 2.f*__builtin_amdgcn_rcpf(e + 1.f);
}
__device__ __forceinline__ void hp_eval(const float* __restrict__ x, int i,
                                        const float* __restrict__ Wp,
                                        const float* __restrict__ bp, float* o){
  float x0 = x[i*3+0], x1 = x[i*3+1], x2 = x[i*3+2];
  #pragma unroll
  for (int j = 0; j < 3; ++j)
    o[j] = fmaxf(x0*Wp[0*3+j] + x1*Wp[1*3+j] + x2*Wp[2*3+j] + bp[j], 0.f);
}

// K1: agg[d] = max(agg[d], hp[s]) — agg PADDED to stride 4 (16B aligned).
// Poison (0xAA = negative) loses to hp>=0 under int atomicMax and to fmaxf.
__global__ void k_edge(const float* __restrict__ x, const int* __restrict__ ei,
                       const float* __restrict__ Wp, const float* __restrict__ bp,
                       float* __restrict__ agg, float* __restrict__ acc,
                       unsigned* __restrict__ counter, int E){
  if (blockIdx.x == 0 && threadIdx.x == 0){ acc[0] = 0.f; counter[0] = 0u; }
  int e = blockIdx.x*blockDim.x + threadIdx.x;
  if (e >= E) return;
  int s = ei[e], d = ei[E+e];
  float o[3]; hp_eval(x, s, Wp, bp, o);
  #pragma unroll
  for (int j = 0; j < 3; ++j)
    if (o[j] > 0.f && o[j] > agg[d*4+j])
      atomicMax((int*)&agg[d*4+j], __float_as_int(o[j]));
}

// K2: h_i = tanh(x@Ws + max(agg_i, hp_i)@Wn + bc), in-place over padded agg.
// Writes lane 3 = 0 so k_mega's dwordx4 reads are defined. libm tanhf kept
// (h feeds the selection scores — stays bit-identical).
__global__ void k_h2(const float* __restrict__ x, float* __restrict__ hb,
                     const float* __restrict__ Wp, const float* __restrict__ bp,
                     const float* __restrict__ Ws, const float* __restrict__ Wn,
                     const float* __restrict__ bc, int N){
  int i = blockIdx.x*blockDim.x + threadIdx.x;
  if (i >= N) return;
  float hp[3]; hp_eval(x, i, Wp, bp, hp);
  float x0 = x[i*3+0], x1 = x[i*3+1], x2 = x[i*3+2];
  float a0 = fmaxf(hb[i*4+0], hp[0]);
  float a1 = fmaxf(hb[i*4+1], hp[1]);
  float a2 = fmaxf(hb[i*4+2], hp[2]);
  float o[3];
  #pragma unroll
  for (int j = 0; j < 3; ++j){
    float v = x0*Ws[0*3+j] + x1*Ws[1*3+j] + x2*Ws[2*3+j]
            + a0*Wn[0*3+j] + a1*Wn[1*3+j] + a2*Wn[2*3+j] + bc[j];
    o[j] = tanhf(v);
  }
  float4 hv; hv.x = o[0]; hv.y = o[1]; hv.z = o[2]; hv.w = 0.f;
  *reinterpret_cast<float4*>(&hb[i*4]) = hv;
}

// K_mega: one 1024-thr block per pathway (grid=P=300).
// A: EP aggregation (LDS, rank-compressed). A4 re-zeroes cnt => hist pre-zeroed.
// S: SAMPLE 1024 scores -> approximate [lo,hi] for t0 linear bins (clamped
//    edge bins catch outliers; exactness preserved via refinement with true
//    s_mn/s_mx and the existing degenerate fallbacks).
// B: fused sweep — score -> sp, min/max, t0 HIST (sampled bins), gate totals.
// Select: pick t0 (hist already built) -> compact (float4, fused drop-subtract)
//    -> single-wave 4-pass radix (pre-zeroed regions) -> candidate fix => uT.
__global__ void __launch_bounds__(BS)
k_mega(const float* __restrict__ h, const int* __restrict__ pe,
       const float* __restrict__ sWl, const float* __restrict__ sbl, const float* __restrict__ sWr,
       const float* __restrict__ pWrel, const float* __restrict__ pWroot, const float* __restrict__ pB,
       const float* __restrict__ gW, const float* __restrict__ gB,
       const float* __restrict__ linW, const float* __restrict__ linb,
       const float* __restrict__ mlpW, const float* __restrict__ mlpb,
       float* __restrict__ spG, float* __restrict__ acc, unsigned* __restrict__ counter,
       unsigned* __restrict__ out, int N, int EP, int K, int P){
  __shared__ unsigned bm[BMW];
  __shared__ int      wpfx[BMW];
  __shared__ float    msum[MAXM*4];   // stride-4: ds_read_b128 per rank
  __shared__ unsigned scrA[NB];       // cnt -> hist (2048 bins / 4x256-bin radix)
  __shared__ unsigned scrB[NB];       // adot -> cand keys
  __shared__ unsigned candIdx[NB];    // candidate node indices
  __shared__ float    wredf[(BS/64)*2];
  __shared__ float    wredA[(BS/64)*4];
  __shared__ float    wredB[(BS/64)*4];
  __shared__ float    s_mn, s_mx;
  __shared__ float    s_slo, s_sscl;  // sampled t0 bin range
  __shared__ float    rlo[3], rsc[3];
  __shared__ int      rb[3];
  __shared__ int      s_r, s_C, s_cc, s_done, s_fused;
  __shared__ unsigned s_uT;

  const int p = blockIdx.x;
  const int tid = threadIdx.x;

  float Wl[9], Wr[9], bl[3], wrel[3], wroot[3], gw[3];
  #pragma unroll
  for (int j = 0; j < 9; ++j){ Wl[j] = sWl[p*9+j]; Wr[j] = sWr[p*9+j]; }
  #pragma unroll
  for (int j = 0; j < 3; ++j){
    bl[j] = sbl[p*3+j]; wrel[j] = pWrel[p*3+j];
    wroot[j] = pWroot[p*3+j]; gw[j] = gW[p*3+j];
  }
  float pbv = pB[p], gbv = gB[p];
  float* sp = spG + (size_t)p*N;

  int*      cnt  = (int*)scrA;
  float*    adot = (float*)scrB;
  unsigned* hist = scrA;              // overlays cnt (A4 re-zeroes => t0-ready)
  unsigned* cand = scrB;              // overlays adot after B

  for (int s = tid; s < MAXM; s += BS){
    cnt[s] = 0; adot[s] = 0.f;
    float4 z; z.x = 0.f; z.y = 0.f; z.z = 0.f; z.w = 0.f;
    *reinterpret_cast<float4*>(&msum[s*4]) = z;
  }
  for (int s = tid; s < BMW; s += BS) bm[s] = 0u;
  if (tid == 0){ s_done = 0; s_fused = 0; s_uT = 0u; }
  __syncthreads();

  const int* ps = pe + (size_t)p*2*EP;
  const int* pd = ps + EP;

  // A1: mark dst nodes
  for (int e = tid; e < EP; e += BS) atomicOr(&bm[pd[e]>>5], 1u << (pd[e]&31));
  __syncthreads();
  // A2: popcount + exclusive prefix (single-wave shfl scan)
  if (tid < 64){
    int l = tid, base = l*10;
    int c[10], s = 0;
    #pragma unroll
    for (int q = 0; q < 10; ++q){ c[q] = __popc(bm[base+q]); s += c[q]; }
    int pre = s;
    #pragma unroll
    for (int off = 1; off < 64; off <<= 1){
      int t = __shfl_up(pre, off);
      if (l >= off) pre += t;
    }
    pre -= s;
    #pragma unroll
    for (int q = 0; q < 10; ++q){ wpfx[base+q] = pre; pre += c[q]; }
  }
  __syncthreads();
  // A3: msum/cnt keyed by rank(dst); h read as dwordx4
  for (int e = tid; e < EP; e += BS){
    int s = ps[e], d = pd[e];
    int r = wpfx[d>>5] + __popc(bm[d>>5] & ((1u << (d&31)) - 1u));
    float4 hs = *reinterpret_cast<const float4*>(&h[s*4]);
    atomicAdd(&cnt[r], 1);
    atomicAdd(&msum[r*4+0], hs.x);
    atomicAdd(&msum[r*4+1], hs.y);
    atomicAdd(&msum[r*4+2], hs.z);
  }
  __syncthreads();
  // A4: msum -> mean; re-zero cnt (cnt==hist storage => t0 hist pre-zeroed)
  for (int r = tid; r < MAXM; r += BS){
    int c = cnt[r];
    cnt[r] = 0;
    if (c > 0){
      float inv = 1.f / (float)c;
      msum[r*4+0] *= inv; msum[r*4+1] *= inv; msum[r*4+2] *= inv;
    }
  }
  __syncthreads();
  // A5: adot[rank(d)] += xc(s) . wrel
  for (int e = tid; e < EP; e += BS){
    int s = ps[e], d = pd[e];
    float m0=0.f,m1=0.f,m2=0.f;
    unsigned w = bm[s>>5];
    if ((w >> (s&31)) & 1u){
      int rs = wpfx[s>>5] + __popc(w & ((1u << (s&31)) - 1u));
      float4 mv = *reinterpret_cast<const float4*>(&msum[rs*4]);
      m0 = mv.x; m1 = mv.y; m2 = mv.z;
    }
    float4 hv = *reinterpret_cast<const float4*>(&h[s*4]);
    float h0 = hv.x, h1 = hv.y, h2 = hv.z;
    float x0 = fmaxf(m0*Wl[0]+m1*Wl[3]+m2*Wl[6] + bl[0] + h0*Wr[0]+h1*Wr[3]+h2*Wr[6], 0.f);
    float x1 = fmaxf(m0*Wl[1]+m1*Wl[4]+m2*Wl[7] + bl[1] + h0*Wr[1]+h1*Wr[4]+h2*Wr[7], 0.f);
    float x2 = fmaxf(m0*Wl[2]+m1*Wl[5]+m2*Wl[8] + bl[2] + h0*Wr[2]+h1*Wr[5]+h2*Wr[8], 0.f);
    int rd = wpfx[d>>5] + __popc(bm[d>>5] & ((1u << (d&31)) - 1u));
    atomicAdd(&adot[rd], x0*wrel[0] + x1*wrel[1] + x2*wrel[2]);
  }
  __syncthreads();

  // S: sample BS strided scores -> t0 bin range (approximate; clamped edges)
  {
    int i = (int)(((long long)tid * (long long)N) / BS);
    float m0=0.f,m1=0.f,m2=0.f,ad=0.f;
    unsigned w = bm[i>>5];
    if ((w >> (i&31)) & 1u){
      int r = wpfx[i>>5] + __popc(w & ((1u << (i&31)) - 1u));
      float4 mv = *reinterpret_cast<const float4*>(&msum[r*4]);
      m0 = mv.x; m1 = mv.y; m2 = mv.z;
      ad = adot[r];
    }
    float4 hv = *reinterpret_cast<const float4*>(&h[i*4]);
    float h0 = hv.x, h1 = hv.y, h2 = hv.z;
    float x0 = fmaxf(m0*Wl[0]+m1*Wl[3]+m2*Wl[6] + bl[0] + h0*Wr[0]+h1*Wr[3]+h2*Wr[6], 0.f);
    float x1 = fmaxf(m0*Wl[1]+m1*Wl[4]+m2*Wl[7] + bl[1] + h0*Wr[1]+h1*Wr[4]+h2*Wr[7], 0.f);
    float x2 = fmaxf(m0*Wl[2]+m1*Wl[5]+m2*Wl[8] + bl[2] + h0*Wr[2]+h1*Wr[5]+h2*Wr[8], 0.f);
    float sc = ad + x0*wroot[0]+x1*wroot[1]+x2*wroot[2] + pbv;
    float smn = sc, smx = sc;
    #pragma unroll
    for (int off = 32; off > 0; off >>= 1){
      smn = fminf(smn, __shfl_down(smn, off));
      smx = fmaxf(smx, __shfl_down(smx, off));
    }
    if ((tid & 63) == 0){ int w2 = tid >> 6; wredf[w2*2+0] = smn; wredf[w2*2+1] = smx; }
    __syncthreads();
    if (tid == 0){
      float a = 3.0e38f, b = -3.0e38f;
      for (int w2 = 0; w2 < BS/64; ++w2){
        a = fminf(a, wredf[w2*2+0]); b = fmaxf(b, wredf[w2*2+1]);
      }
      float span = b - a;
      if (!(span > 0.f)) span = fabsf(a)*1e-6f + 1e-30f;   // degenerate sample
      s_slo = a; s_sscl = 2047.0f / span;
    }
    __syncthreads();
  }
  // pin sampled range to SGPRs (wave-uniform) — protects the VGPR=64 budget
  float lo0, scl0;
  {
    unsigned ulo = __builtin_amdgcn_readfirstlane(__float_as_uint(s_slo));
    unsigned usc = __builtin_amdgcn_readfirstlane(__float_as_uint(s_sscl));
    lo0 = __uint_as_float(ulo); scl0 = __uint_as_float(usc);
  }

  // B: fused sweep — score -> sp, min/max, t0 hist (sampled bins), gate totals
  float mn = 3.0e38f, mx = -3.0e38f;
  float tl = 0.f, ta0 = 0.f, ta1 = 0.f, ta2 = 0.f;
  for (int i = tid; i < N; i += BS){
    float m0=0.f,m1=0.f,m2=0.f,ad=0.f;
    unsigned w = bm[i>>5];
    if ((w >> (i&31)) & 1u){
      int r = wpfx[i>>5] + __popc(w & ((1u << (i&31)) - 1u));
      float4 mv = *reinterpret_cast<const float4*>(&msum[r*4]);
      m0 = mv.x; m1 = mv.y; m2 = mv.z;
      ad = adot[r];
    }
    float4 hv = *reinterpret_cast<const float4*>(&h[i*4]);
    float h0 = hv.x, h1 = hv.y, h2 = hv.z;
    float x0 = fmaxf(m0*Wl[0]+m1*Wl[3]+m2*Wl[6] + bl[0] + h0*Wr[0]+h1*Wr[3]+h2*Wr[6], 0.f);
    float x1 = fmaxf(m0*Wl[1]+m1*Wl[4]+m2*Wl[7] + bl[1] + h0*Wr[1]+h1*Wr[4]+h2*Wr[7], 0.f);
    float x2 = fmaxf(m0*Wl[2]+m1*Wl[5]+m2*Wl[8] + bl[2] + h0*Wr[2]+h1*Wr[5]+h2*Wr[8], 0.f);
    float sc = ad + x0*wroot[0]+x1*wroot[1]+x2*wroot[2] + pbv;
    sp[i] = sc;
    atomicAdd(&hist[lbin(sc, lo0, scl0)], 1u);
    mn = fminf(mn, sc); mx = fmaxf(mx, sc);
    float tt = fast_tanh(sc);
    float g = fminf(fmaxf(tt*(x0*gw[0]+x1*gw[1]+x2*gw[2]) + gbv, -60.f), 60.f);
    float e = __expf(g);
    float et = e * tt;
    tl += e; ta0 += et*x0; ta1 += et*x1; ta2 += et*x2;
  }
  #pragma unroll
  for (int off = 32; off > 0; off >>= 1){
    mn  = fminf(mn, __shfl_down(mn, off));
    mx  = fmaxf(mx, __shfl_down(mx, off));
    tl  += __shfl_down(tl,  off); ta0 += __shfl_down(ta0, off);
    ta1 += __shfl_down(ta1, off); ta2 += __shfl_down(ta2, off);
  }
  if ((tid & 63) == 0){
    int w = tid >> 6;
    wredf[w*2+0] = mn; wredf[w*2+1] = mx;
    wredA[w*4+0]=tl; wredA[w*4+1]=ta0; wredA[w*4+2]=ta1; wredA[w*4+3]=ta2;
  }
  __syncthreads();
  if (tid == 0){
    float a = 3.0e38f, b = -3.0e38f;
    for (int w = 0; w < BS/64; ++w){ a = fminf(a, wredf[w*2+0]); b = fmaxf(b, wredf[w*2+1]); }
    s_mn = a; s_mx = b; s_r = K;
    if (!(b > a)){ s_uT = fkey(a); s_done = 1; s_fused = 1; }  // all equal: none dropped
  }
  __syncthreads();

  float dl = 0.f, d0 = 0.f, d1 = 0.f, d2 = 0.f;   // drop-sum registers

  for (int t = 0; t < 3; ++t){
    __syncthreads();
    if (s_done) break;
    float lo, scl;
    if (t == 0){
      lo = s_slo; scl = s_sscl;     // hist already built during B
    } else {
      float plo = rlo[t-1], pscl = rsc[t-1]; int pb = rb[t-1];
      lo = plo + pb/pscl;
      float hi = plo + (pb+1)/pscl;
      if (t == 1){                   // sampled-range edge buckets: true span
        if (pb == 0)    lo = s_mn;
        if (pb == NB-1) hi = s_mx;
      }
      scl = 2047.0f / (hi - lo);
      if (!(hi > lo) || !(scl < 1e37f)){
        if (tid == 0){ s_uT = fkey(lo); s_done = 1; }   // collapsed: all == lo
        __syncthreads();
        continue;
      }
      for (int b = tid; b < NB; b += BS) hist[b] = 0u;
      __syncthreads();
      for (int i = tid; i < N; i += BS){
        float sc = sp[i];
        bool act = true;
        for (int q = 0; q < t; ++q) act = act && (lbin(sc, rlo[q], rsc[q]) == rb[q]);
        if (act) atomicAdd(&hist[lbin(sc, lo, scl)], 1u);
      }
      __syncthreads();
    }
    // pick over 2048 bins: lane l owns bins [32l, 32l+32)
    if (tid < 64){
      int l = tid;
      unsigned s = 0;
      for (int q = 0; q < 32; ++q) s += hist[l*32+q];
      unsigned S = s;
      #pragma unroll
      for (int off = 1; off < 64; off <<= 1){
        unsigned u2 = __shfl_down(S, off);
        if (l + off < 64) S += u2;
      }
      unsigned suf = S - s;               // suffix over lanes > l
      unsigned r = (unsigned)s_r;
      int b = -1; unsigned sufnext = 0, cb = 0;
      for (int q = 31; q >= 0; --q){
        unsigned c = hist[l*32+q];
        unsigned nsuf = suf + c;
        if (nsuf >= r && suf < r){ b = l*32+q; sufnext = suf; cb = c; }
        suf = nsuf;
      }
      if (b >= 0){
        rb[t] = b; rlo[t] = lo; rsc[t] = scl;
        s_r = (int)(r - sufnext);
        s_C = (int)cb;
      }
    }
    __syncthreads();
    int C = s_C;
    if (C <= NB){
      // pre-zero the 4x256 radix regions (hist dead after pick) + reset s_cc
      if (tid < 1024) hist[tid] = 0u;
      if (tid == 0) s_cc = 0;
      __syncthreads();
      // compact: candidates (key+idx) AND drop-sum accumulation in one sweep.
      // t==0 fast path: float4 loads, single-bin predicate.
      if (t == 0 && (N & 3) == 0){
        const int b0 = rb[0];
        const float l0 = rlo[0], s0 = rsc[0];
        int G = N >> 2;
        for (int g = tid; g < G; g += BS){
          float4 v = ((const float4*)sp)[g];
          #pragma unroll
          for (int u = 0; u < 4; ++u){
            float sc = (u==0)?v.x:((u==1)?v.y:((u==2)?v.z:v.w));
            int b = lbin(sc, l0, s0);
            if (b == b0){
              int ix = atomicAdd(&s_cc, 1);
              if (ix < NB){ cand[ix] = fkey(sc); candIdx[ix] = (unsigned)(g*4+u); }
            } else if (b < b0){
              int i = g*4+u;
              float m0=0.f,m1=0.f,m2=0.f;
              unsigned w = bm[i>>5];
              if ((w >> (i&31)) & 1u){
                int r = wpfx[i>>5] + __popc(w & ((1u << (i&31)) - 1u));
                float4 mv = *reinterpret_cast<const float4*>(&msum[r*4]);
                m0 = mv.x; m1 = mv.y; m2 = mv.z;
              }
              float4 hv = *reinterpret_cast<const float4*>(&h[i*4]);
              float h0 = hv.x, h1 = hv.y, h2 = hv.z;
              float x0 = fmaxf(m0*Wl[0]+m1*Wl[3]+m2*Wl[6] + bl[0] + h0*Wr[0]+h1*Wr[3]+h2*Wr[6], 0.f);
              float x1 = fmaxf(m0*Wl[1]+m1*Wl[4]+m2*Wl[7] + bl[1] + h0*Wr[1]+h1*Wr[4]+h2*Wr[7], 0.f);
              float x2 = fmaxf(m0*Wl[2]+m1*Wl[5]+m2*Wl[8] + bl[2] + h0*Wr[2]+h1*Wr[5]+h2*Wr[8], 0.f);
              float tt = fast_tanh(sc);
              float gg = fminf(fmaxf(tt*(x0*gw[0]+x1*gw[1]+x2*gw[2]) + gbv, -60.f), 60.f);
              float e = __expf(gg);
              float et = e * tt;
              dl += e; d0 += et*x0; d1 += et*x1; d2 += et*x2;
            }
          }
        }
      } else {
        for (int i = tid; i < N; i += BS){
          float sc = sp[i];
          bool iscand = true, isdrop = false;
          for (int q = 0; q <= t; ++q){
            int b = lbin(sc, rlo[q], rsc[q]);
            if (b != rb[q]){ iscand = false; isdrop = (b < rb[q]); break; }
          }
          if (iscand){
            int ix = atomicAdd(&s_cc, 1);
            if (ix < NB){ cand[ix] = fkey(sc); candIdx[ix] = (unsigned)i; }
          } else if (isdrop){
            float m0=0.f,m1=0.f,m2=0.f;
            unsigned w = bm[i>>5];
            if ((w >> (i&31)) & 1u){
              int r = wpfx[i>>5] + __popc(w & ((1u << (i&31)) - 1u));
              float4 mv = *reinterpret_cast<const float4*>(&msum[r*4]);
              m0 = mv.x; m1 = mv.y; m2 = mv.z;
            }
            float4 hv = *reinterpret_cast<const float4*>(&h[i*4]);
            float h0 = hv.x, h1 = hv.y, h2 = hv.z;
            float x0 = fmaxf(m0*Wl[0]+m1*Wl[3]+m2*Wl[6] + bl[0] + h0*Wr[0]+h1*Wr[3]+h2*Wr[6], 0.f);
            float x1 = fmaxf(m0*Wl[1]+m1*Wl[4]+m2*Wl[7] + bl[1] + h0*Wr[1]+h1*Wr[4]+h2*Wr[7], 0.f);
            float x2 = fmaxf(m0*Wl[2]+m1*Wl[5]+m2*Wl[8] + bl[2] + h0*Wr[2]+h1*Wr[5]+h2*Wr[8], 0.f);
            float tt = fast_tanh(sc);
            float gg = fminf(fmaxf(tt*(x0*gw[0]+x1*gw[1]+x2*gw[2]) + gbv, -60.f), 60.f);
            float e = __expf(gg);
            float et = e * tt;
            dl += e; d0 += et*x0; d1 += et*x1; d2 += et*x2;
          }
        }
      }
      __syncthreads();
      // exact 4-pass radix over cand[0..C), single wave, pre-zeroed regions
      if (tid < 64){
        int l = tid;
        unsigned pref = 0u, mask = 0u;
        int r = s_r;
        #pragma unroll
        for (int pass = 0; pass < 4; ++pass){
          int shift = 24 - 8*pass;
          unsigned* hp = hist + (pass << 8);
          for (int j = l; j < C; j += 64){
            unsigned u = cand[j];
            if ((u & mask) == pref) atomicAdd(&hp[(u>>shift)&255u], 1u);
          }
          asm volatile("s_waitcnt lgkmcnt(0)" ::: "memory");
          unsigned h0 = hp[4*l+0], h1 = hp[4*l+1], h2 = hp[4*l+2], h3 = hp[4*l+3];
          unsigned ssum = h0+h1+h2+h3;
          unsigned S = ssum;
          #pragma unroll
          for (int off = 1; off < 64; off <<= 1){
            unsigned u2 = __shfl_down(S, off);
            if (l + off < 64) S += u2;
          }
          unsigned Snext = S - ssum;
          unsigned rr = (unsigned)r;
          unsigned suf3 = h3 + Snext;
          unsigned suf2 = h2 + suf3;
          unsigned suf1 = h1 + suf2;
          unsigned suf0 = h0 + suf1;
          int b = -1; unsigned sufn = 0;
          if      (suf3 >= rr && Snext < rr){ b = 4*l+3; sufn = Snext; }
          else if (suf2 >= rr && suf3  < rr){ b = 4*l+2; sufn = suf3; }
          else if (suf1 >= rr && suf2  < rr){ b = 4*l+1; sufn = suf2; }
          else if (suf0 >= rr && suf1  < rr){ b = 4*l+0; sufn = suf1; }
          unsigned long long ball = __ballot(b >= 0);
          int src = __ffsll(ball) - 1;
          b    = __shfl(b, src);
          sufn = (unsigned)__shfl((int)sufn, src);
          pref |= (unsigned)b << shift;
          mask |= 255u << shift;
          r = (int)(rr - sufn);
        }
        if (l == 0) s_uT = pref;
      }
      if (tid == 0){ s_done = 1; s_fused = 1; }
      __syncthreads();
      // candidate fix: subtract in-bucket dropped (key < uT)
      {
        const unsigned uTl = s_uT;
        for (int j = tid; j < C; j += BS){
          if (cand[j] < uTl){
            int i = (int)candIdx[j];
            float sc = sp[i];
            float m0=0.f,m1=0.f,m2=0.f;
            unsigned w = bm[i>>5];
            if ((w >> (i&31)) & 1u){
              int r = wpfx[i>>5] + __popc(w & ((1u << (i&31)) - 1u));
              float4 mv = *reinterpret_cast<const float4*>(&msum[r*4]);
              m0 = mv.x; m1 = mv.y; m2 = mv.z;
            }
            float4 hv = *reinterpret_cast<const float4*>(&h[i*4]);
            float h0 = hv.x, h1 = hv.y, h2 = hv.z;
            float x0 = fmaxf(m0*Wl[0]+m1*Wl[3]+m2*Wl[6] + bl[0] + h0*Wr[0]+h1*Wr[3]+h2*Wr[6], 0.f);
            float x1 = fmaxf(m0*Wl[1]+m1*Wl[4]+m2*Wl[7] + bl[1] + h0*Wr[1]+h1*Wr[4]+h2*Wr[7], 0.f);
            float x2 = fmaxf(m0*Wl[2]+m1*Wl[5]+m2*Wl[8] + bl[2] + h0*Wr[2]+h1*Wr[5]+h2*Wr[8], 0.f);
            float tt = fast_tanh(sc);
            float gg = fminf(fmaxf(tt*(x0*gw[0]+x1*gw[1]+x2*gw[2]) + gbv, -60.f), 60.f);
            float e = __expf(gg);
            float et = e * tt;
            dl += e; d0 += et*x0; d1 += et*x1; d2 += et*x2;
          }
        }
      }
    } else if (t == 2){
      if (tid == 0){ s_uT = fkey(lo + rb[t]/scl); s_done = 1; }  // safety; s_fused=0
      __syncthreads();
    }
  }
  __syncthreads();
  const unsigned uT = s_uT;

  // Fallback correction (rare degenerate paths only): full N sweep
  if (!s_fused){
    for (int i = tid; i < N; i += BS){
      float sc = sp[i];
      if (fkey(sc) < uT){
        float m0=0.f,m1=0.f,m2=0.f;
        unsigned w = bm[i>>5];
        if ((w >> (i&31)) & 1u){
          int r = wpfx[i>>5] + __popc(w & ((1u << (i&31)) - 1u));
          float4 mv = *reinterpret_cast<const float4*>(&msum[r*4]);
          m0 = mv.x; m1 = mv.y; m2 = mv.z;
        }
        float4 hv = *reinterpret_cast<const float4*>(&h[i*4]);
        float h0 = hv.x, h1 = hv.y, h2 = hv.z;
        float x0 = fmaxf(m0*Wl[0]+m1*Wl[3]+m2*Wl[6] + bl[0] + h0*Wr[0]+h1*Wr[3]+h2*Wr[6], 0.f);
        float x1 = fmaxf(m0*Wl[1]+m1*Wl[4]+m2*Wl[7] + bl[1] + h0*Wr[1]+h1*Wr[4]+h2*Wr[7], 0.f);
        float x2 = fmaxf(m0*Wl[2]+m1*Wl[5]+m2*Wl[8] + bl[2] + h0*Wr[2]+h1*Wr[5]+h2*Wr[8], 0.f);
        float tt = fast_tanh(sc);
        float gg = fminf(fmaxf(tt*(x0*gw[0]+x1*gw[1]+x2*gw[2]) + gbv, -60.f), 60.f);
        float e = __expf(gg);
        float et = e * tt;
        dl += e; d0 += et*x0; d1 += et*x1; d2 += et*x2;
      }
    }
  }
  #pragma unroll
  for (int off = 32; off > 0; off >>= 1){
    dl += __shfl_down(dl, off); d0 += __shfl_down(d0, off);
    d1 += __shfl_down(d1, off); d2 += __shfl_down(d2, off);
  }
  if ((tid & 63) == 0){
    int w = tid >> 6;
    wredB[w*4+0]=dl; wredB[w*4+1]=d0; wredB[w*4+2]=d1; wredB[w*4+3]=d2;
  }
  __syncthreads();
  if (tid == 0){
    float L=0.f, A0=0.f, A1=0.f, A2=0.f;
    for (int w = 0; w < BS/64; ++w){
      L  += wredA[w*4+0] - wredB[w*4+0];
      A0 += wredA[w*4+1] - wredB[w*4+1];
      A1 += wredA[w*4+2] - wredB[w*4+2];
      A2 += wredA[w*4+3] - wredB[w*4+3];
    }
    float inv = 1.f / L;
    float r0 = fmaxf(A0*inv, 0.f);
    float r1 = fmaxf(A1*inv, 0.f);
    float r2 = fmaxf(A2*inv, 0.f);
    float rr = fmaxf(r0*linW[0] + r1*linW[1] + r2*linW[2] + linb[0], 0.f);
    atomicAdd(acc, rr * mlpW[p]);            // relu(relu(x)) == relu(x)
    __threadfence();
    unsigned old = atomicAdd(counter, 1u);
    if (old == (unsigned)(P-1)){
      __threadfence();
      float z = atomicAdd(acc, 0.f) + mlpb[0];   // atomic read: full sum visible
      float a = 1.f / (1.f + expf(-z));
      unsigned A = __float_as_uint(a);
      unsigned B = (A + 0x7FFFu + ((A >> 16) & 1u)) >> 16;   // bf16 RNE bits
      out[0] = (A & 0xFFFF0000u) | (B & 0xFFFFu);            // dual-format store
    }
  }
}

// ================= launcher: 3 dispatches =================
extern "C" void kernel_launch(void* const* d_in, const int* in_sizes, int n_in,
                              void* d_out, int out_size, void* d_ws, size_t ws_size,
                              hipStream_t stream){
  const float* x      = (const float*)d_in[0];
  const int*   ei     = (const int*)  d_in[1];
  const int*   pe     = (const int*)  d_in[2];
  const float* W_pool = (const float*)d_in[3];
  const float* b_pool = (const float*)d_in[4];
  const float* W_self = (const float*)d_in[5];
  const float* W_neigh= (const float*)d_in[6];
  const float* b_conv = (const float*)d_in[7];
  const float* sWl    = (const float*)d_in[8];
  const float* sbl    = (const float*)d_in[9];
  const float* sWr    = (const float*)d_in[10];
  const float* pWrel  = (const float*)d_in[11];
  const float* pWroot = (const float*)d_in[12];
  const float* pB     = (const float*)d_in[13];
  const float* gW     = (const float*)d_in[14];
  const float* gB     = (const float*)d_in[15];
  const float* linW   = (const float*)d_in[16];
  const float* linb   = (const float*)d_in[17];
  const float* mlpW   = (const float*)d_in[18];
  const float* mlpb   = (const float*)d_in[19];

  const int N  = in_sizes[0] / 3;
  const int E  = in_sizes[1] / 2;
  const int P  = in_sizes[13];
  const int EP = in_sizes[2] / (2 * P);
  const int K  = (4*N + 4) / 5;          // ceil(0.8*N)

  // ws layout (float elements): [0]=acc, [1]=counter, pad;
  // [16,16+4N)=agg/h (PADDED stride-4, 16B aligned); sp after.
  float*    ws      = (float*)d_ws;
  float*    acc     = ws;
  unsigned* counter = (unsigned*)(ws + 1);
  float*    agg     = ws + 16;           // becomes h in-place after k_h2
  float*    h       = agg;
  float*    spG     = ws + 16 + (size_t)4*N;

  k_edge<<<(E+255)/256, 256, 0, stream>>>(x, ei, W_pool, b_pool, agg, acc, counter, E);
  k_h2  <<<(N+255)/256, 256, 0, stream>>>(x, agg, W_pool, b_pool,
                                          W_self, W_neigh, b_conv, N);
  k_mega<<<P, BS, 0, stream>>>(h, pe, sWl, sbl, sWr, pWrel, pWroot, pB, gW, gB,
                               linW, linb, mlpW, mlpb,
                               spG, acc, counter, (unsigned*)d_out, N, EP, K, P);
}